// Round 3
// baseline (331.653 us; speedup 1.0000x reference)
//
#include <hip/hip_runtime.h>
#include <hip/hip_fp16.h>

#define N_S 50000
#define N_A 50000
#define E_A 800000
#define E_S 800000
#define HID 128
#define XD 32
#define UD 16

#define KF_PX 176    // projX virtual K: [x32 | h128 | ps2 | pad14]
#define KF_G 192     // final virtual K: [h128 | x32 | tail32]
#define CAP 48       // fixed per-node CSR slot capacity (deg ~Poisson(16), max ~38)
#define CNTSTRIDE 16 // 32-bit counters padded to one per 64B line (16 uints)
#define DISQ 65535.0f

#define BM 64
#define BK 16
#define EPT 4        // edges per scatter thread
#define PROJ_NB ((N_S + BM - 1) / BM)                    // 782
#define SCAT_NB_S ((E_S + 256 * EPT - 1) / (256 * EPT))  // 782
#define SCAT_NB_A ((E_A + 256 * EPT - 1) / (256 * EPT))  // 782

// ---------------- K1: zero counters + build fused weights ----------------
__global__ void prep_kernel(const float* __restrict__ Wu2h, const float* __restrict__ bu2h,
                            const float* __restrict__ Wx2h, const float* __restrict__ bx2h,
                            const float* __restrict__ Wupd, const float* __restrict__ bupd,
                            float* __restrict__ WXsrc, float* __restrict__ WG,
                            unsigned* __restrict__ cntS, unsigned* __restrict__ cntA) {
    int idx = blockIdx.x * blockDim.x + threadIdx.x;
    if (idx < N_S) {
        cntS[(size_t)idx * CNTSTRIDE] = 0u;
        cntA[(size_t)idx * CNTSTRIDE] = 0u;
    }
    if (idx >= (KF_PX + KF_G) * HID) return;
    int r = idx >> 7, j = idx & 127;
    if (r < KF_PX) {
        float v = 0.f;
        if (r < 162) {
            const float* a = Wx2h + (size_t)r * HID;
            float acc = 0.f;
            for (int k = 0; k < HID; ++k) acc += a[k] * Wupd[(258 + k) * HID + j];
            v = acc;
        }
        WXsrc[(size_t)r * HID + j] = v;
        return;
    }
    r -= KF_PX;
    float v = 0.f;
    if (r < 128) {
        v = Wupd[(2 + r) * HID + j];
    } else if (r < 160) {
        v = Wupd[(386 + r - 128) * HID + j];
    } else if (r < 162) {
        v = Wupd[(r - 160) * HID + j];
    } else if (r < 184) {
        const float* a;
        if (r < 180)      a = Wu2h + (size_t)(r - 162) * HID;
        else if (r == 180) a = Wu2h + (size_t)20 * HID;
        else if (r < 183)  a = Wu2h + (size_t)(18 + r - 181) * HID;
        else               a = bu2h;
        float acc = 0.f;
        for (int k = 0; k < HID; ++k) acc += a[k] * Wupd[(130 + k) * HID + j];
        v = acc;
    } else if (r < 188) {
        const float* a;
        if (r < 186)      a = Wx2h + (size_t)(162 + r - 184) * HID;
        else if (r == 186) a = bx2h;
        else               a = Wx2h + (size_t)164 * HID;
        float acc = 0.f;
        for (int k = 0; k < HID; ++k) acc += a[k] * Wupd[(258 + k) * HID + j];
        v = acc;
    } else if (r == 188) {
        v = bupd[j];
    }
    WG[(size_t)r * HID + j] = v;
}

// ---------------- K2a: scatterhist (standalone for attribution) ----------------
// 32-bit count atomic; slot word = (dis_q16 << 16) | src (both srcs < 65536).
__global__ __launch_bounds__(256) void scat_kernel(
        const int* __restrict__ srcS, const int* __restrict__ dstS, const float* __restrict__ disS,
        const int* __restrict__ srcA, const int* __restrict__ dstA, const float* __restrict__ disA,
        unsigned* __restrict__ cntS, unsigned* __restrict__ cntA,
        unsigned* __restrict__ slotS, unsigned* __restrict__ slotA) {
    int tid = threadIdx.x;
    int bid2 = blockIdx.x;
    const int* src; const int* dst; const float* dis;
    unsigned* cnt; unsigned* slot; int nE; int base;
    if (bid2 < SCAT_NB_S) {
        src = srcS; dst = dstS; dis = disS; cnt = cntS; slot = slotS;
        nE = E_S; base = bid2 * (256 * EPT);
    } else {
        src = srcA; dst = dstA; dis = disA; cnt = cntA; slot = slotA;
        nE = E_A; base = (bid2 - SCAT_NB_S) * (256 * EPT);
    }
    unsigned wv[EPT]; int dv[EPT];
#pragma unroll
    for (int r = 0; r < EPT; ++r) {
        int t = base + r * 256 + tid;
        bool ok = t < nE;
        int tt = ok ? t : 0;
        int s = __builtin_nontemporal_load(src + tt);
        int d = __builtin_nontemporal_load(dst + tt);
        float f = __builtin_nontemporal_load(dis + tt);
        dv[r] = ok ? d : -1;
        wv[r] = ((unsigned)(f * DISQ + 0.5f) << 16) | (unsigned)s;
    }
    unsigned old[EPT];
#pragma unroll
    for (int r = 0; r < EPT; ++r) {
        if (dv[r] >= 0) old[r] = atomicAdd(cnt + (size_t)dv[r] * CNTSTRIDE, 1u);
    }
#pragma unroll
    for (int r = 0; r < EPT; ++r) {
        if (dv[r] >= 0 && old[r] < CAP) slot[(size_t)dv[r] * CAP + old[r]] = wv[r];
    }
}

// ---------------- K2b: projX GEMM (standalone) ----------------
__global__ __launch_bounds__(256) void proj_kernel(
        const float* __restrict__ x, const float* __restrict__ h, const float* __restrict__ ps,
        const float* __restrict__ WXsrc, __half* __restrict__ PX) {
    __shared__ float As[BK][BM];
    __shared__ float Bs[BK][HID];
    int tid = threadIdx.x;
    int m0 = blockIdx.x * BM;
    int tm = tid >> 5, tn = tid & 31;
    float acc[8][4] = {};
    int la_m = tid >> 2;
    int la_k = (tid & 3) * 4;
    for (int kc = 0; kc < KF_PX; kc += BK) {
        int gm = m0 + la_m;
        int k = kc + la_k;
        float4 av = make_float4(0.f, 0.f, 0.f, 0.f);
        if (gm < N_S) {
            if (k < 32)        av = *(const float4*)(x + (size_t)gm * XD + k);
            else if (k < 160)  av = *(const float4*)(h + (size_t)gm * HID + (k - 32));
            else if (k == 160) av = make_float4(ps[gm * 2], ps[gm * 2 + 1], 0.f, 0.f);
        }
        As[la_k + 0][la_m] = av.x;
        As[la_k + 1][la_m] = av.y;
        As[la_k + 2][la_m] = av.z;
        As[la_k + 3][la_m] = av.w;
#pragma unroll
        for (int t2 = 0; t2 < 2; ++t2) {
            int i = tid * 2 + t2;
            int bk = i >> 5, bn = (i & 31) * 4;
            *(float4*)&Bs[bk][bn] = *(const float4*)(WXsrc + (size_t)(kc + bk) * HID + bn);
        }
        __syncthreads();
#pragma unroll
        for (int k2 = 0; k2 < BK; ++k2) {
            float4 a0 = *(float4*)&As[k2][tm * 8];
            float4 a1 = *(float4*)&As[k2][tm * 8 + 4];
            float4 b0 = *(float4*)&Bs[k2][tn * 4];
            float am[8] = {a0.x, a0.y, a0.z, a0.w, a1.x, a1.y, a1.z, a1.w};
            float bv[4] = {b0.x, b0.y, b0.z, b0.w};
#pragma unroll
            for (int i = 0; i < 8; ++i)
#pragma unroll
                for (int j = 0; j < 4; ++j)
                    acc[i][j] += am[i] * bv[j];
        }
        __syncthreads();
    }
    for (int i = 0; i < 8; ++i) {
        int gm = m0 + tm * 8 + i;
        if (gm < N_S) {
            __half2* row = (__half2*)(PX + (size_t)gm * HID);
            row[tn * 2]     = __floats2half2_rn(acc[i][0], acc[i][1]);
            row[tn * 2 + 1] = __floats2half2_rn(acc[i][2], acc[i][3]);
        }
    }
}

// ---------------- K3: aggregate (no LDS, high occupancy) ----------------
__global__ __launch_bounds__(256) void aggregate_kernel(
        const float* __restrict__ ps, const float* __restrict__ u, const float* __restrict__ pa,
        const __half2* __restrict__ PX2,
        const unsigned* __restrict__ cntS, const unsigned* __restrict__ slotS,
        const unsigned* __restrict__ cntA, const unsigned* __restrict__ slotA,
        float* __restrict__ aggPXs, float* __restrict__ Gtail) {
    int wv = threadIdx.x >> 6, lane = threadIdx.x & 63;
    int n = blockIdx.x * 4 + wv;
    if (n >= N_S) return;

    int cS = (int)cntS[(size_t)n * CNTSTRIDE];
    int cA = (int)cntA[(size_t)n * CNTSTRIDE];
    int cSc = cS < CAP ? cS : CAP;
    int cAc = cA < CAP ? cA : CAP;

    // slot words: (dis_q16 << 16) | src
    unsigned mywS = (lane < cSc) ? slotS[(size_t)n * CAP + lane] : 0u;
    unsigned mywA = (lane < cAc) ? slotA[(size_t)n * CAP + lane] : 0u;

    // dis sums via wave reduction of the high halves
    int dqS = (int)(mywS >> 16);
    int dqA = (int)(mywA >> 16);
#pragma unroll
    for (int off = 1; off < 64; off <<= 1) {
        dqS += __shfl_xor(dqS, off);
        dqA += __shfl_xor(dqA, off);
    }
    float sumDisS = (float)dqS * (1.0f / DISQ);
    float sumDisA = (float)dqA * (1.0f / DISQ);

    // ---- s2s: sum projected fp16 rows, 8-deep independent load batches ----
    int myidxS = (int)(mywS & 0xFFFFu);
    float ax = 0.f, ay = 0.f;
    int rounds = (cSc + 7) & ~7;
    for (int j = 0; j < rounds; j += 8) {
        float2 f[8];
        float w[8];
#pragma unroll
        for (int t = 0; t < 8; ++t) {
            int jj = j + t;
            int s = __shfl(myidxS, jj);
            f[t] = __half22float2(PX2[(size_t)s * 64 + lane]);
            w[t] = (jj < cSc) ? 1.f : 0.f;
        }
#pragma unroll
        for (int t = 0; t < 8; ++t) {
            ax += w[t] * f[t].x;
            ay += w[t] * f[t].y;
        }
    }
    float invd = cS > 0 ? 1.f / (float)cS : 0.f;
    *(float2*)(aggPXs + (size_t)n * HID + lane * 2) = make_float2(ax * invd, ay * invd);

    // ---- a2s: raw [u16 | pa2] sums; 4 lane-groups x 4 edges in parallel ----
    int g = lane >> 4, l = lane & 15;
    int myidxA = (int)(mywA & 0xFFFFu);
    float uacc = 0.f, paacc = 0.f;
    int iters = (cAc + 3) >> 2;
    for (int it = 0; it < iters; ++it) {
        int jj = it * 4 + g;
        int s = __shfl(myidxA, jj < 64 ? jj : 0);
        float w = (jj < cAc) ? 1.f : 0.f;
        uacc += w * u[(size_t)s * UD + l];
        if (l < 2) paacc += w * pa[s * 2 + l];
    }
    uacc += __shfl_xor(uacc, 16);
    uacc += __shfl_xor(uacc, 32);
    paacc += __shfl_xor(paacc, 16);
    paacc += __shfl_xor(paacc, 32);
    float us  = __shfl(uacc, (lane >= 2 && lane < 18) ? lane - 2 : 0);
    float pas = __shfl(paacc, (lane >= 18 && lane < 20) ? lane - 18 : 0);

    // ---- Gtail (32 cols) ----
    float psv0 = ps[n * 2], psv1 = ps[n * 2 + 1];
    float e = cS > 0 ? 1.f : 0.f;
    float fcA = (float)cA;
    float v = 0.f;
    if (lane == 0)       v = psv0;
    else if (lane == 1)  v = psv1;
    else if (lane < 18)  v = us;
    else if (lane < 20)  v = pas;
    else if (lane == 20) v = sumDisA;
    else if (lane == 21) v = fcA * psv0;
    else if (lane == 22) v = fcA * psv1;
    else if (lane == 23) v = fcA;
    else if (lane == 24) v = e * psv0;
    else if (lane == 25) v = e * psv1;
    else if (lane == 26) v = e;
    else if (lane == 27) v = invd * sumDisS;
    else if (lane == 28) v = 1.f;
    if (lane < 32) Gtail[(size_t)n * 32 + lane] = v;
}

// ---------------- K4: final GEMM: out = [h|x|Gtail] @ WG + aggPXs ----------------
__global__ __launch_bounds__(256) void gemmF_kernel(const float* __restrict__ h,
                                                    const float* __restrict__ x,
                                                    const float* __restrict__ Gtail,
                                                    const float* __restrict__ WG,
                                                    const float* __restrict__ aggPXs,
                                                    float* __restrict__ C) {
    __shared__ float As[BK][BM];
    __shared__ float Bs[BK][HID];
    int tid = threadIdx.x;
    int m0 = blockIdx.x * BM;
    int tm = tid >> 5, tn = tid & 31;
    float acc[8][4] = {};
    int la_m = tid >> 2;
    int la_k = (tid & 3) * 4;
    for (int kc = 0; kc < KF_G; kc += BK) {
        int gm = m0 + la_m;
        int k = kc + la_k;
        float4 av = make_float4(0.f, 0.f, 0.f, 0.f);
        if (gm < N_S) {
            if (k < 128)      av = *(const float4*)(h + (size_t)gm * HID + k);
            else if (k < 160) av = *(const float4*)(x + (size_t)gm * XD + (k - 128));
            else              av = *(const float4*)(Gtail + (size_t)gm * 32 + (k - 160));
        }
        As[la_k + 0][la_m] = av.x;
        As[la_k + 1][la_m] = av.y;
        As[la_k + 2][la_m] = av.z;
        As[la_k + 3][la_m] = av.w;
#pragma unroll
        for (int t = 0; t < 2; ++t) {
            int i = tid * 2 + t;
            int bk = i >> 5, bn = (i & 31) * 4;
            *(float4*)&Bs[bk][bn] = *(const float4*)(WG + (size_t)(kc + bk) * HID + bn);
        }
        __syncthreads();
#pragma unroll
        for (int k2 = 0; k2 < BK; ++k2) {
            float4 a0 = *(float4*)&As[k2][tm * 8];
            float4 a1 = *(float4*)&As[k2][tm * 8 + 4];
            float4 b0 = *(float4*)&Bs[k2][tn * 4];
            float am[8] = {a0.x, a0.y, a0.z, a0.w, a1.x, a1.y, a1.z, a1.w};
            float bv[4] = {b0.x, b0.y, b0.z, b0.w};
#pragma unroll
            for (int i = 0; i < 8; ++i)
#pragma unroll
                for (int j = 0; j < 4; ++j)
                    acc[i][j] += am[i] * bv[j];
        }
        __syncthreads();
    }
    for (int i = 0; i < 8; ++i) {
        int gm = m0 + tm * 8 + i;
        if (gm < N_S) {
            float4 ag = *(const float4*)(aggPXs + (size_t)gm * HID + tn * 4);
            *(float4*)(C + (size_t)gm * HID + tn * 4) =
                make_float4(acc[i][0] + ag.x, acc[i][1] + ag.y,
                            acc[i][2] + ag.z, acc[i][3] + ag.w);
        }
    }
}

extern "C" void kernel_launch(void* const* d_in, const int* in_sizes, int n_in,
                              void* d_out, int out_size, void* d_ws, size_t ws_size,
                              hipStream_t stream) {
    const float* h     = (const float*)d_in[0];
    const float* x     = (const float*)d_in[1];
    const float* u     = (const float*)d_in[2];
    const float* ps    = (const float*)d_in[3];
    const float* pa    = (const float*)d_in[4];
    const float* dis_a = (const float*)d_in[5];
    const float* dis_s = (const float*)d_in[6];
    const int* a2s_src = (const int*)d_in[7];
    const int* a2s_dst = (const int*)d_in[8];
    const int* s2s_src = (const int*)d_in[9];
    const int* s2s_dst = (const int*)d_in[10];
    const float* Wu2h  = (const float*)d_in[11];
    const float* bu2h  = (const float*)d_in[12];
    const float* Wx2h  = (const float*)d_in[13];
    const float* bx2h  = (const float*)d_in[14];
    const float* Wupd  = (const float*)d_in[15];
    const float* bupd  = (const float*)d_in[16];
    float* out = (float*)d_out;

    // Workspace layout (70.59 MB total):
    char* ws = (char*)d_ws;
    unsigned* cntS   = (unsigned*)(ws + 0);          // 50000*64B = 3.2 MB (padded, 32-bit used)
    unsigned* cntA   = (unsigned*)(ws + 3200000);    // 3.2 MB
    unsigned* slotS  = (unsigned*)(ws + 6400000);    // 50000*48*4 = 9.6 MB
    unsigned* slotA  = (unsigned*)(ws + 16000000);   // 9.6 MB
    __half* PX    = (__half*)(ws + 25600000);        // 12.8 MB
    float* aggPXs = (float*)(ws + 38400000);         // 25.6 MB
    float* Gtail  = (float*)(ws + 64000000);         // 6.4 MB
    float* WXsrc  = (float*)(ws + 70400000);         // 90,112 B
    float* WG     = (float*)(ws + 70490112);         // 98,304 B

    // K1: zero counters + build WXsrc/WG
    prep_kernel<<<196, 256, 0, stream>>>(Wu2h, bu2h, Wx2h, bx2h, Wupd, bupd,
                                         WXsrc, WG, cntS, cntA);

    // K2a: scatterhist (standalone for per-kernel attribution)
    scat_kernel<<<SCAT_NB_S + SCAT_NB_A, 256, 0, stream>>>(
        s2s_src, s2s_dst, dis_s, a2s_src, a2s_dst, dis_a,
        cntS, cntA, slotS, slotA);

    // K2b: projX
    proj_kernel<<<PROJ_NB, 256, 0, stream>>>(x, h, ps, WXsrc, PX);

    // K3: aggregate
    aggregate_kernel<<<(N_S + 3) / 4, 256, 0, stream>>>(
        ps, u, pa, (const __half2*)PX,
        cntS, slotS, cntA, slotA,
        aggPXs, Gtail);

    // K4: final GEMM
    gemmF_kernel<<<PROJ_NB, 256, 0, stream>>>(h, x, Gtail, WG, aggPXs, out);
}

// Round 4
// 292.006 us; speedup vs baseline: 1.1358x; 1.1358x over previous
//
#include <hip/hip_runtime.h>
#include <hip/hip_fp16.h>

#define N_S 50000
#define N_A 50000
#define E_A 800000
#define E_S 800000
#define HID 128
#define XD 32
#define UD 16

#define KF_PX 176    // projX virtual K: [x32 | h128 | ps2 | pad14]
#define KF_G 192     // final virtual K: [h128 | x32 | tail32]
#define CAP 48       // fixed per-node CSR slot capacity (deg ~Poisson(16), max ~38)
#define CNTSTRIDE 16 // 32-bit counters padded to one per 64B line (16 uints)
#define DISQ 65535.0f

#define BM 64
#define BK 16
#define EPT 4        // edges per scatter thread
#define PROJ_NB ((N_S + BM - 1) / BM)                    // 782
#define SCAT_NB_S ((E_S + 256 * EPT - 1) / (256 * EPT))  // 782
#define SCAT_NB_A ((E_A + 256 * EPT - 1) / (256 * EPT))  // 782

typedef _Float16 f16x8 __attribute__((ext_vector_type(8)));
typedef float f32x4 __attribute__((ext_vector_type(4)));

// ---------------- K1: zero counters + build fused weights ----------------
// WGh is stored in MFMA B-fragment order: WGh[((kb*8+nt)*64 + lane)*8 + j]
// = WG_true[32*kb + (lane>>4)*8 + j][16*nt + (lane&15)]   (fp16)
__global__ void prep_kernel(const float* __restrict__ Wu2h, const float* __restrict__ bu2h,
                            const float* __restrict__ Wx2h, const float* __restrict__ bx2h,
                            const float* __restrict__ Wupd, const float* __restrict__ bupd,
                            float* __restrict__ WXsrc, _Float16* __restrict__ WGh,
                            unsigned* __restrict__ cntS, unsigned* __restrict__ cntA) {
    int idx = blockIdx.x * blockDim.x + threadIdx.x;
    if (idx < N_S) {
        cntS[(size_t)idx * CNTSTRIDE] = 0u;
        cntA[(size_t)idx * CNTSTRIDE] = 0u;
    }
    if (idx >= (KF_PX + KF_G) * HID) return;
    int r = idx >> 7, j = idx & 127;
    if (r < KF_PX) {
        float v = 0.f;
        if (r < 162) {
            const float* a = Wx2h + (size_t)r * HID;
            float acc = 0.f;
            for (int k = 0; k < HID; ++k) acc += a[k] * Wupd[(258 + k) * HID + j];
            v = acc;
        }
        WXsrc[(size_t)r * HID + j] = v;
        return;
    }
    r -= KF_PX;
    float v = 0.f;
    if (r < 128) {
        v = Wupd[(2 + r) * HID + j];
    } else if (r < 160) {
        v = Wupd[(386 + r - 128) * HID + j];
    } else if (r < 162) {
        v = Wupd[(r - 160) * HID + j];
    } else if (r < 184) {
        const float* a;
        if (r < 180)      a = Wu2h + (size_t)(r - 162) * HID;
        else if (r == 180) a = Wu2h + (size_t)20 * HID;
        else if (r < 183)  a = Wu2h + (size_t)(18 + r - 181) * HID;
        else               a = bu2h;
        float acc = 0.f;
        for (int k = 0; k < HID; ++k) acc += a[k] * Wupd[(130 + k) * HID + j];
        v = acc;
    } else if (r < 188) {
        const float* a;
        if (r < 186)      a = Wx2h + (size_t)(162 + r - 184) * HID;
        else if (r == 186) a = bx2h;
        else               a = Wx2h + (size_t)164 * HID;
        float acc = 0.f;
        for (int k = 0; k < HID; ++k) acc += a[k] * Wupd[(258 + k) * HID + j];
        v = acc;
    } else if (r == 188) {
        v = bupd[j];
    }
    // scatter into MFMA B-fragment layout
    int kb = r >> 5, rr = r & 31;
    int lanehi = rr >> 3, j8 = rr & 7;
    int nt = j >> 4, lanelo = j & 15;
    size_t off = (((size_t)(kb * 8 + nt) * 64) + lanehi * 16 + lanelo) * 8 + j8;
    WGh[off] = (_Float16)v;
}

// ---------------- K2: projX GEMM blocks (0..781) + scatterhist blocks (782..2345) ----------------
// scat: 32-bit count atomic; slot word = (dis_q16 << 16) | src (both srcs < 65536).
__global__ __launch_bounds__(256) void phase1_kernel(
        const float* __restrict__ x, const float* __restrict__ h, const float* __restrict__ ps,
        const float* __restrict__ WXsrc, __half* __restrict__ PX,
        const int* __restrict__ srcS, const int* __restrict__ dstS, const float* __restrict__ disS,
        const int* __restrict__ srcA, const int* __restrict__ dstA, const float* __restrict__ disA,
        unsigned* __restrict__ cntS, unsigned* __restrict__ cntA,
        unsigned* __restrict__ slotS, unsigned* __restrict__ slotA) {
    __shared__ float As[BK][BM];
    __shared__ float Bs[BK][HID];
    int tid = threadIdx.x;

    if (blockIdx.x >= PROJ_NB) {
        int bid2 = blockIdx.x - PROJ_NB;
        const int* src; const int* dst; const float* dis;
        unsigned* cnt; unsigned* slot; int nE; int base;
        if (bid2 < SCAT_NB_S) {
            src = srcS; dst = dstS; dis = disS; cnt = cntS; slot = slotS;
            nE = E_S; base = bid2 * (256 * EPT);
        } else {
            src = srcA; dst = dstA; dis = disA; cnt = cntA; slot = slotA;
            nE = E_A; base = (bid2 - SCAT_NB_S) * (256 * EPT);
        }
        unsigned wv[EPT]; int dv[EPT];
#pragma unroll
        for (int r = 0; r < EPT; ++r) {
            int t = base + r * 256 + tid;
            bool ok = t < nE;
            int tt = ok ? t : 0;
            int s = __builtin_nontemporal_load(src + tt);
            int d = __builtin_nontemporal_load(dst + tt);
            float f = __builtin_nontemporal_load(dis + tt);
            dv[r] = ok ? d : -1;
            wv[r] = ((unsigned)(f * DISQ + 0.5f) << 16) | (unsigned)s;
        }
        unsigned old[EPT];
#pragma unroll
        for (int r = 0; r < EPT; ++r) {
            if (dv[r] >= 0) old[r] = atomicAdd(cnt + (size_t)dv[r] * CNTSTRIDE, 1u);
        }
#pragma unroll
        for (int r = 0; r < EPT; ++r) {
            if (dv[r] >= 0 && old[r] < CAP)
                __builtin_nontemporal_store(wv[r], slot + (size_t)dv[r] * CAP + old[r]);
        }
        return;
    }

    // ---- projX: PX[N_S x 128] (fp16) = [x|h|ps] @ WXsrc ----
    int m0 = blockIdx.x * BM;
    int tm = tid >> 5, tn = tid & 31;
    float acc[8][4] = {};
    int la_m = tid >> 2;
    int la_k = (tid & 3) * 4;
    for (int kc = 0; kc < KF_PX; kc += BK) {
        int gm = m0 + la_m;
        int k = kc + la_k;
        float4 av = make_float4(0.f, 0.f, 0.f, 0.f);
        if (gm < N_S) {
            if (k < 32)        av = *(const float4*)(x + (size_t)gm * XD + k);
            else if (k < 160)  av = *(const float4*)(h + (size_t)gm * HID + (k - 32));
            else if (k == 160) av = make_float4(ps[gm * 2], ps[gm * 2 + 1], 0.f, 0.f);
        }
        As[la_k + 0][la_m] = av.x;
        As[la_k + 1][la_m] = av.y;
        As[la_k + 2][la_m] = av.z;
        As[la_k + 3][la_m] = av.w;
#pragma unroll
        for (int t2 = 0; t2 < 2; ++t2) {
            int i = tid * 2 + t2;
            int bk = i >> 5, bn = (i & 31) * 4;
            *(float4*)&Bs[bk][bn] = *(const float4*)(WXsrc + (size_t)(kc + bk) * HID + bn);
        }
        __syncthreads();
#pragma unroll
        for (int k2 = 0; k2 < BK; ++k2) {
            float4 a0 = *(float4*)&As[k2][tm * 8];
            float4 a1 = *(float4*)&As[k2][tm * 8 + 4];
            float4 b0 = *(float4*)&Bs[k2][tn * 4];
            float am[8] = {a0.x, a0.y, a0.z, a0.w, a1.x, a1.y, a1.z, a1.w};
            float bv[4] = {b0.x, b0.y, b0.z, b0.w};
#pragma unroll
            for (int i = 0; i < 8; ++i)
#pragma unroll
                for (int j = 0; j < 4; ++j)
                    acc[i][j] += am[i] * bv[j];
        }
        __syncthreads();
    }
    for (int i = 0; i < 8; ++i) {
        int gm = m0 + tm * 8 + i;
        if (gm < N_S) {
            __half2* row = (__half2*)(PX + (size_t)gm * HID);
            row[tn * 2]     = __floats2half2_rn(acc[i][0], acc[i][1]);
            row[tn * 2 + 1] = __floats2half2_rn(acc[i][2], acc[i][3]);
        }
    }
}

// ---------------- K3: aggregate (no LDS, high occupancy) ----------------
__global__ __launch_bounds__(256) void aggregate_kernel(
        const float* __restrict__ ps, const float* __restrict__ u, const float* __restrict__ pa,
        const __half2* __restrict__ PX2,
        const unsigned* __restrict__ cntS, const unsigned* __restrict__ slotS,
        const unsigned* __restrict__ cntA, const unsigned* __restrict__ slotA,
        float* __restrict__ aggPXs, float* __restrict__ Gtail) {
    int wv = threadIdx.x >> 6, lane = threadIdx.x & 63;
    int n = blockIdx.x * 4 + wv;
    if (n >= N_S) return;

    int cS = (int)cntS[(size_t)n * CNTSTRIDE];
    int cA = (int)cntA[(size_t)n * CNTSTRIDE];
    int cSc = cS < CAP ? cS : CAP;
    int cAc = cA < CAP ? cA : CAP;

    unsigned mywS = (lane < cSc) ? slotS[(size_t)n * CAP + lane] : 0u;
    unsigned mywA = (lane < cAc) ? slotA[(size_t)n * CAP + lane] : 0u;

    int dqS = (int)(mywS >> 16);
    int dqA = (int)(mywA >> 16);
#pragma unroll
    for (int off = 1; off < 64; off <<= 1) {
        dqS += __shfl_xor(dqS, off);
        dqA += __shfl_xor(dqA, off);
    }
    float sumDisS = (float)dqS * (1.0f / DISQ);
    float sumDisA = (float)dqA * (1.0f / DISQ);

    // ---- s2s: sum projected fp16 rows, 8-deep independent load batches ----
    int myidxS = (int)(mywS & 0xFFFFu);
    float ax = 0.f, ay = 0.f;
    int rounds = (cSc + 7) & ~7;
    for (int j = 0; j < rounds; j += 8) {
        float2 f[8];
        float w[8];
#pragma unroll
        for (int t = 0; t < 8; ++t) {
            int jj = j + t;
            int s = __shfl(myidxS, jj);
            f[t] = __half22float2(PX2[(size_t)s * 64 + lane]);
            w[t] = (jj < cSc) ? 1.f : 0.f;
        }
#pragma unroll
        for (int t = 0; t < 8; ++t) {
            ax += w[t] * f[t].x;
            ay += w[t] * f[t].y;
        }
    }
    float invd = cS > 0 ? 1.f / (float)cS : 0.f;
    *(float2*)(aggPXs + (size_t)n * HID + lane * 2) = make_float2(ax * invd, ay * invd);

    // ---- a2s: raw [u16 | pa2] sums; 4 lane-groups x 4 edges in parallel ----
    int g = lane >> 4, l = lane & 15;
    int myidxA = (int)(mywA & 0xFFFFu);
    float uacc = 0.f, paacc = 0.f;
    int iters = (cAc + 3) >> 2;
    for (int it = 0; it < iters; ++it) {
        int jj = it * 4 + g;
        int s = __shfl(myidxA, jj < 64 ? jj : 0);
        float w = (jj < cAc) ? 1.f : 0.f;
        uacc += w * u[(size_t)s * UD + l];
        if (l < 2) paacc += w * pa[s * 2 + l];
    }
    uacc += __shfl_xor(uacc, 16);
    uacc += __shfl_xor(uacc, 32);
    paacc += __shfl_xor(paacc, 16);
    paacc += __shfl_xor(paacc, 32);
    float us  = __shfl(uacc, (lane >= 2 && lane < 18) ? lane - 2 : 0);
    float pas = __shfl(paacc, (lane >= 18 && lane < 20) ? lane - 18 : 0);

    // ---- Gtail (32 cols) ----
    float psv0 = ps[n * 2], psv1 = ps[n * 2 + 1];
    float e = cS > 0 ? 1.f : 0.f;
    float fcA = (float)cA;
    float v = 0.f;
    if (lane == 0)       v = psv0;
    else if (lane == 1)  v = psv1;
    else if (lane < 18)  v = us;
    else if (lane < 20)  v = pas;
    else if (lane == 20) v = sumDisA;
    else if (lane == 21) v = fcA * psv0;
    else if (lane == 22) v = fcA * psv1;
    else if (lane == 23) v = fcA;
    else if (lane == 24) v = e * psv0;
    else if (lane == 25) v = e * psv1;
    else if (lane == 26) v = e;
    else if (lane == 27) v = invd * sumDisS;
    else if (lane == 28) v = 1.f;
    if (lane < 32) Gtail[(size_t)n * 32 + lane] = v;
}

// ---------------- K4: final GEMM via fp16 MFMA: out = [h|x|Gtail] @ WG + aggPXs ----------------
// One wave per 16-row tile; no LDS, no barriers. B pre-swizzled into frag order by prep.
// Layout facts used: A-row/B-col = lane&15; D: row=(lane>>4)*4+reg, col=lane&15 [m89].
// K-index map is a free bijection as long as A and B use the same one (contraction symmetry).
__global__ __launch_bounds__(256) void gemmF_kernel(const float* __restrict__ h,
                                                    const float* __restrict__ x,
                                                    const float* __restrict__ Gtail,
                                                    const _Float16* __restrict__ WGh,
                                                    const float* __restrict__ aggPXs,
                                                    float* __restrict__ C) {
    int wid = threadIdx.x >> 6, lane = threadIdx.x & 63;
    int mt = blockIdx.x * 4 + wid;           // 16-row tile id
    int row0 = mt * 16;
    int arow = row0 + (lane & 15);
    if (arow >= N_S) arow = N_S - 1;         // clamp; stores guarded below
    int kh = (lane >> 4) * 8;                // k offset within each 32-block

    const float* hp = h + (size_t)arow * HID;
    const float* xp = x + (size_t)arow * XD;
    const float* gp = Gtail + (size_t)arow * 32;

    f16x8 afrag[6];
#pragma unroll
    for (int kb = 0; kb < 6; ++kb) {
        int k = kb * 32 + kh;
        const float* src;
        if (k < 128)      src = hp + k;
        else if (k < 160) src = xp + (k - 128);
        else              src = gp + (k - 160);
        float4 lo = *(const float4*)(src);
        float4 hi = *(const float4*)(src + 4);
        f16x8 a;
        a[0] = (_Float16)lo.x; a[1] = (_Float16)lo.y;
        a[2] = (_Float16)lo.z; a[3] = (_Float16)lo.w;
        a[4] = (_Float16)hi.x; a[5] = (_Float16)hi.y;
        a[6] = (_Float16)hi.z; a[7] = (_Float16)hi.w;
        afrag[kb] = a;
    }

    const f16x8* Bf = (const f16x8*)WGh;     // [(kb*8+nt)*64 + lane]
#pragma unroll
    for (int nt = 0; nt < 8; ++nt) {
        f32x4 acc = {0.f, 0.f, 0.f, 0.f};
#pragma unroll
        for (int kb = 0; kb < 6; ++kb) {
            f16x8 b = Bf[(size_t)(kb * 8 + nt) * 64 + lane];
            acc = __builtin_amdgcn_mfma_f32_16x16x32_f16(afrag[kb], b, acc, 0, 0, 0);
        }
        int col = nt * 16 + (lane & 15);
        int rbase = row0 + (lane >> 4) * 4;
#pragma unroll
        for (int i = 0; i < 4; ++i) {
            int gr = rbase + i;
            if (gr < N_S) {
                C[(size_t)gr * HID + col] =
                    acc[i] + aggPXs[(size_t)gr * HID + col];
            }
        }
    }
}

extern "C" void kernel_launch(void* const* d_in, const int* in_sizes, int n_in,
                              void* d_out, int out_size, void* d_ws, size_t ws_size,
                              hipStream_t stream) {
    const float* h     = (const float*)d_in[0];
    const float* x     = (const float*)d_in[1];
    const float* u     = (const float*)d_in[2];
    const float* ps    = (const float*)d_in[3];
    const float* pa    = (const float*)d_in[4];
    const float* dis_a = (const float*)d_in[5];
    const float* dis_s = (const float*)d_in[6];
    const int* a2s_src = (const int*)d_in[7];
    const int* a2s_dst = (const int*)d_in[8];
    const int* s2s_src = (const int*)d_in[9];
    const int* s2s_dst = (const int*)d_in[10];
    const float* Wu2h  = (const float*)d_in[11];
    const float* bu2h  = (const float*)d_in[12];
    const float* Wx2h  = (const float*)d_in[13];
    const float* bx2h  = (const float*)d_in[14];
    const float* Wupd  = (const float*)d_in[15];
    const float* bupd  = (const float*)d_in[16];
    float* out = (float*)d_out;

    // Workspace layout (70.54 MB total):
    char* ws = (char*)d_ws;
    unsigned* cntS   = (unsigned*)(ws + 0);          // 3.2 MB (padded, 32-bit used)
    unsigned* cntA   = (unsigned*)(ws + 3200000);    // 3.2 MB
    unsigned* slotS  = (unsigned*)(ws + 6400000);    // 9.6 MB
    unsigned* slotA  = (unsigned*)(ws + 16000000);   // 9.6 MB
    __half* PX    = (__half*)(ws + 25600000);        // 12.8 MB
    float* aggPXs = (float*)(ws + 38400000);         // 25.6 MB
    float* Gtail  = (float*)(ws + 64000000);         // 6.4 MB
    float* WXsrc  = (float*)(ws + 70400000);         // 90,112 B
    _Float16* WGh = (_Float16*)(ws + 70490112);      // 49,152 B (MFMA frag order)

    // K1: zero counters + build WXsrc/WGh
    prep_kernel<<<196, 256, 0, stream>>>(Wu2h, bu2h, Wx2h, bx2h, Wupd, bupd,
                                         WXsrc, WGh, cntS, cntA);

    // K2: projX (blocks 0..781) overlapped with scatterhist (blocks 782..2345)
    phase1_kernel<<<PROJ_NB + SCAT_NB_S + SCAT_NB_A, 256, 0, stream>>>(
        x, h, ps, WXsrc, PX,
        s2s_src, s2s_dst, dis_s, a2s_src, a2s_dst, dis_a,
        cntS, cntA, slotS, slotA);

    // K3: aggregate
    aggregate_kernel<<<(N_S + 3) / 4, 256, 0, stream>>>(
        ps, u, pa, (const __half2*)PX,
        cntS, slotS, cntA, slotA,
        aggPXs, Gtail);

    // K4: final GEMM (MFMA fp16)
    gemmF_kernel<<<PROJ_NB, 256, 0, stream>>>(h, x, Gtail, WGh, aggPXs, out);
}

// Round 5
// 278.908 us; speedup vs baseline: 1.1891x; 1.0470x over previous
//
#include <hip/hip_runtime.h>
#include <hip/hip_fp16.h>

#define N_S 50000
#define N_A 50000
#define E_A 800000
#define E_S 800000
#define HID 128
#define XD 32
#define UD 16

#define KF_PX 176    // projX virtual K: [x32 | h128 | ps2 | pad14]
#define KF_G 192     // final virtual K: [h128 | x32 | tail32]
#define DISQ 65535.0f

#define NBKT 196     // dst buckets of 256 nodes (dst>>8)
#define CAPB 5120    // records per bucket (mean 4082, +16 sigma)
#define CAPN 48      // per-node list cap (deg ~Poisson(16), max ~38)
#define NPB 64       // nodes per s2 block

#define BM 64
#define BK 16
#define EPT 8        // edges per bin thread
#define PROJ_NB ((N_S + BM - 1) / BM)                    // 782
#define BIN_NB ((E_S + 256 * EPT - 1) / (256 * EPT))     // 391 per graph

typedef _Float16 f16x8 __attribute__((ext_vector_type(8)));
typedef float f32x4 __attribute__((ext_vector_type(4)));

// ---------------- K1: zero bucket counters + build fused weights ----------------
// WGh in MFMA B-frag order: WGh[((kb*8+nt)*64 + lane)*8 + j]
//   = WG_true[32*kb + (lane>>4)*8 + j][16*nt + (lane&15)]  (fp16)
__global__ void prep_kernel(const float* __restrict__ Wu2h, const float* __restrict__ bu2h,
                            const float* __restrict__ Wx2h, const float* __restrict__ bx2h,
                            const float* __restrict__ Wupd, const float* __restrict__ bupd,
                            float* __restrict__ WXsrc, _Float16* __restrict__ WGh,
                            unsigned* __restrict__ bktCnt) {
    int idx = blockIdx.x * blockDim.x + threadIdx.x;
    if (idx < 2 * NBKT) bktCnt[idx] = 0u;
    if (idx >= (KF_PX + KF_G) * HID) return;
    int r = idx >> 7, j = idx & 127;
    if (r < KF_PX) {
        float v = 0.f;
        if (r < 162) {
            const float* a = Wx2h + (size_t)r * HID;
            float acc = 0.f;
            for (int k = 0; k < HID; ++k) acc += a[k] * Wupd[(258 + k) * HID + j];
            v = acc;
        }
        WXsrc[(size_t)r * HID + j] = v;
        return;
    }
    r -= KF_PX;
    float v = 0.f;
    if (r < 128) {
        v = Wupd[(2 + r) * HID + j];
    } else if (r < 160) {
        v = Wupd[(386 + r - 128) * HID + j];
    } else if (r < 162) {
        v = Wupd[(r - 160) * HID + j];
    } else if (r < 184) {
        const float* a;
        if (r < 180)      a = Wu2h + (size_t)(r - 162) * HID;
        else if (r == 180) a = Wu2h + (size_t)20 * HID;
        else if (r < 183)  a = Wu2h + (size_t)(18 + r - 181) * HID;
        else               a = bu2h;
        float acc = 0.f;
        for (int k = 0; k < HID; ++k) acc += a[k] * Wupd[(130 + k) * HID + j];
        v = acc;
    } else if (r < 188) {
        const float* a;
        if (r < 186)      a = Wx2h + (size_t)(162 + r - 184) * HID;
        else if (r == 186) a = bx2h;
        else               a = Wx2h + (size_t)164 * HID;
        float acc = 0.f;
        for (int k = 0; k < HID; ++k) acc += a[k] * Wupd[(258 + k) * HID + j];
        v = acc;
    } else if (r == 188) {
        v = bupd[j];
    }
    int kb = r >> 5, rr = r & 31;
    int lanehi = rr >> 3, j8 = rr & 7;
    int nt = j >> 4, lanelo = j & 15;
    size_t off = (((size_t)(kb * 8 + nt) * 64) + lanehi * 16 + lanelo) * 8 + j8;
    WGh[off] = (_Float16)v;
}

// ---------------- K2: projX GEMM (blocks 0..781) + edge binning (blocks 782..1563) -------
// bin: record = (bucket<<48)|(disq<<24)|(src<<8)|dstLocal; LDS-hist + LDS-ordered staging,
// one global atomic per (block,bucket), ~coalesced 8B-record segment flush.
__global__ __launch_bounds__(256) void phase1_kernel(
        const float* __restrict__ x, const float* __restrict__ h, const float* __restrict__ ps,
        const float* __restrict__ WXsrc, __half* __restrict__ PX,
        const int* __restrict__ srcS, const int* __restrict__ dstS, const float* __restrict__ disS,
        const int* __restrict__ srcA, const int* __restrict__ dstA, const float* __restrict__ disA,
        unsigned* __restrict__ bktCnt,
        unsigned long long* __restrict__ bktS, unsigned long long* __restrict__ bktA) {
    __shared__ unsigned long long sbuf[2432];   // 19456 B, unioned between paths
    int tid = threadIdx.x;

    if (blockIdx.x >= PROJ_NB) {
        int bid2 = blockIdx.x - PROJ_NB;
        const int* src; const int* dst; const float* dis;
        unsigned long long* bkt; unsigned* bcnt; int nE, base;
        if (bid2 < BIN_NB) {
            src = srcS; dst = dstS; dis = disS; bkt = bktS; bcnt = bktCnt;
            nE = E_S; base = bid2 * (256 * EPT);
        } else {
            src = srcA; dst = dstA; dis = disA; bkt = bktA; bcnt = bktCnt + NBKT;
            nE = E_A; base = (bid2 - BIN_NB) * (256 * EPT);
        }
        unsigned long long* recs = sbuf;                 // 2048 records
        unsigned* hist  = (unsigned*)(sbuf + 2048);      // 256
        unsigned* scan  = hist + 256;                    // 256
        unsigned* gbase = hist + 512;                    // 256

        hist[tid] = 0u;
        __syncthreads();

        unsigned long long rec[EPT]; int bk[EPT]; unsigned rank[EPT];
#pragma unroll
        for (int r = 0; r < EPT; ++r) {
            int t = base + r * 256 + tid;
            bool ok = t < nE;
            int tt = ok ? t : 0;
            int s = __builtin_nontemporal_load(src + tt);
            int d = __builtin_nontemporal_load(dst + tt);
            float f = __builtin_nontemporal_load(dis + tt);
            unsigned disq = (unsigned)(f * DISQ + 0.5f);
            bk[r] = ok ? (d >> 8) : -1;
            rec[r] = ((unsigned long long)(d >> 8) << 48) |
                     ((unsigned long long)disq << 24) |
                     ((unsigned long long)(unsigned)s << 8) |
                     (unsigned long long)(d & 255);
        }
#pragma unroll
        for (int r = 0; r < EPT; ++r)
            if (bk[r] >= 0) rank[r] = atomicAdd(&hist[bk[r]], 1u);
        __syncthreads();

        // inclusive scan of hist -> scan
        scan[tid] = hist[tid];
        __syncthreads();
        for (int off = 1; off < 256; off <<= 1) {
            unsigned v = scan[tid];
            unsigned add = (tid >= off) ? scan[tid - off] : 0u;
            __syncthreads();
            scan[tid] = v + add;
            __syncthreads();
        }

        // stage records LDS-ordered by bucket
#pragma unroll
        for (int r = 0; r < EPT; ++r) {
            if (bk[r] >= 0) {
                unsigned pos = scan[bk[r]] - hist[bk[r]] + rank[r];
                recs[pos] = rec[r];
            }
        }
        // reserve global space per bucket
        if (tid < NBKT) {
            unsigned c = hist[tid];
            gbase[tid] = c ? atomicAdd(&bcnt[tid], c) : 0u;
        }
        __syncthreads();

        int total = (int)scan[255];
        for (int p = tid; p < total; p += 256) {
            unsigned long long rr = recs[p];
            int bb = (int)(rr >> 48);
            unsigned gi = gbase[bb] + (unsigned)p - (scan[bb] - hist[bb]);
            if (gi < CAPB) bkt[(size_t)bb * CAPB + gi] = rr;
        }
        return;
    }

    // ---- projX: PX[N_S x 128] (fp16) = [x|h|ps] @ WXsrc ----
    float* As = (float*)sbuf;            // [BK][BM]
    float* Bs = As + BK * BM;            // [BK][HID]
    int m0 = blockIdx.x * BM;
    int tm = tid >> 5, tn = tid & 31;
    float acc[8][4] = {};
    int la_m = tid >> 2;
    int la_k = (tid & 3) * 4;
    for (int kc = 0; kc < KF_PX; kc += BK) {
        int gm = m0 + la_m;
        int k = kc + la_k;
        float4 av = make_float4(0.f, 0.f, 0.f, 0.f);
        if (gm < N_S) {
            if (k < 32)        av = *(const float4*)(x + (size_t)gm * XD + k);
            else if (k < 160)  av = *(const float4*)(h + (size_t)gm * HID + (k - 32));
            else if (k == 160) av = make_float4(ps[gm * 2], ps[gm * 2 + 1], 0.f, 0.f);
        }
        As[(la_k + 0) * BM + la_m] = av.x;
        As[(la_k + 1) * BM + la_m] = av.y;
        As[(la_k + 2) * BM + la_m] = av.z;
        As[(la_k + 3) * BM + la_m] = av.w;
#pragma unroll
        for (int t2 = 0; t2 < 2; ++t2) {
            int i = tid * 2 + t2;
            int bkk = i >> 5, bn = (i & 31) * 4;
            *(float4*)&Bs[bkk * HID + bn] = *(const float4*)(WXsrc + (size_t)(kc + bkk) * HID + bn);
        }
        __syncthreads();
#pragma unroll
        for (int k2 = 0; k2 < BK; ++k2) {
            float4 a0 = *(float4*)&As[k2 * BM + tm * 8];
            float4 a1 = *(float4*)&As[k2 * BM + tm * 8 + 4];
            float4 b0 = *(float4*)&Bs[k2 * HID + tn * 4];
            float am[8] = {a0.x, a0.y, a0.z, a0.w, a1.x, a1.y, a1.z, a1.w};
            float bv[4] = {b0.x, b0.y, b0.z, b0.w};
#pragma unroll
            for (int i = 0; i < 8; ++i)
#pragma unroll
                for (int j = 0; j < 4; ++j)
                    acc[i][j] += am[i] * bv[j];
        }
        __syncthreads();
    }
    for (int i = 0; i < 8; ++i) {
        int gm = m0 + tm * 8 + i;
        if (gm < N_S) {
            __half2* row = (__half2*)(PX + (size_t)gm * HID);
            row[tn * 2]     = __floats2half2_rn(acc[i][0], acc[i][1]);
            row[tn * 2 + 1] = __floats2half2_rn(acc[i][2], acc[i][3]);
        }
    }
}

// ---------------- K3: per-bucket LDS CSR build + aggregate ----------------
// block = (bucket, 64-node subrange); scans bucket records of both graphs,
// builds per-node lists in LDS, then waves aggregate 16 nodes each.
__global__ __launch_bounds__(256) void s2_kernel(
        const float* __restrict__ ps, const float* __restrict__ u, const float* __restrict__ pa,
        const __half2* __restrict__ PX2,
        const unsigned* __restrict__ bktCnt,
        const unsigned long long* __restrict__ bktS, const unsigned long long* __restrict__ bktA,
        float* __restrict__ aggPXs, float* __restrict__ Gtail) {
    int b = blockIdx.x >> 2, sub = blockIdx.x & 3;
    int n0 = b * 256 + sub * 64;
    if (n0 >= N_S) return;
    int tid = threadIdx.x;

    __shared__ unsigned listS[NPB * CAPN];   // 12 KB
    __shared__ unsigned listA[NPB * CAPN];   // 12 KB
    __shared__ unsigned cntL[2][NPB];
    __shared__ unsigned disL[2][NPB];

    if (tid < 128) {
        cntL[tid >> 6][tid & 63] = 0u;
        disL[tid >> 6][tid & 63] = 0u;
    }
    __syncthreads();

    for (int g = 0; g < 2; ++g) {
        const unsigned long long* bp = (g ? bktA : bktS) + (size_t)b * CAPB;
        unsigned cnt = bktCnt[g * NBKT + b];
        if (cnt > CAPB) cnt = CAPB;
        for (unsigned e = tid; e < cnt; e += 256) {
            unsigned long long rr = bp[e];
            int dl = (int)(rr & 255);
            if ((dl >> 6) == sub) {
                int l = dl & 63;
                unsigned disq = (unsigned)((rr >> 24) & 0xFFFF);
                unsigned w = (disq << 16) | (unsigned)((rr >> 8) & 0xFFFF);
                unsigned rk = atomicAdd(&cntL[g][l], 1u);
                atomicAdd(&disL[g][l], disq);
                if (rk < CAPN) {
                    if (g) listA[l * CAPN + rk] = w;
                    else   listS[l * CAPN + rk] = w;
                }
            }
        }
    }
    __syncthreads();

    int wv = tid >> 6, lane = tid & 63;
    for (int i = 0; i < 16; ++i) {
        int l = wv * 16 + i;
        int n = n0 + l;
        if (n >= N_S) break;
        int cS = (int)cntL[0][l];
        int cA = (int)cntL[1][l];
        float sumDisS = (float)disL[0][l] * (1.0f / DISQ);
        float sumDisA = (float)disL[1][l] * (1.0f / DISQ);
        int cSc = cS < CAPN ? cS : CAPN;
        int cAc = cA < CAPN ? cA : CAPN;

        unsigned mywS = (lane < cSc) ? listS[l * CAPN + lane] : 0u;
        unsigned mywA = (lane < cAc) ? listA[l * CAPN + lane] : 0u;

        // ---- s2s: sum projected fp16 rows, 8-deep independent load batches ----
        int myidxS = (int)(mywS & 0xFFFFu);
        float ax = 0.f, ay = 0.f;
        int rounds = (cSc + 7) & ~7;
        for (int j = 0; j < rounds; j += 8) {
            float2 f[8];
            float w[8];
#pragma unroll
            for (int t = 0; t < 8; ++t) {
                int jj = j + t;
                int s = __shfl(myidxS, jj);
                f[t] = __half22float2(PX2[(size_t)s * 64 + lane]);
                w[t] = (jj < cSc) ? 1.f : 0.f;
            }
#pragma unroll
            for (int t = 0; t < 8; ++t) {
                ax += w[t] * f[t].x;
                ay += w[t] * f[t].y;
            }
        }
        float invd = cS > 0 ? 1.f / (float)cS : 0.f;
        *(float2*)(aggPXs + (size_t)n * HID + lane * 2) = make_float2(ax * invd, ay * invd);

        // ---- a2s: raw [u16 | pa2] sums; 4 lane-groups x 4 edges in parallel ----
        int g2 = lane >> 4, ll = lane & 15;
        int myidxA = (int)(mywA & 0xFFFFu);
        float uacc = 0.f, paacc = 0.f;
        int iters = (cAc + 3) >> 2;
        for (int it = 0; it < iters; ++it) {
            int jj = it * 4 + g2;
            int s = __shfl(myidxA, jj < 64 ? jj : 0);
            float w = (jj < cAc) ? 1.f : 0.f;
            uacc += w * u[(size_t)s * UD + ll];
            if (ll < 2) paacc += w * pa[s * 2 + ll];
        }
        uacc += __shfl_xor(uacc, 16);
        uacc += __shfl_xor(uacc, 32);
        paacc += __shfl_xor(paacc, 16);
        paacc += __shfl_xor(paacc, 32);
        float us  = __shfl(uacc, (lane >= 2 && lane < 18) ? lane - 2 : 0);
        float pas = __shfl(paacc, (lane >= 18 && lane < 20) ? lane - 18 : 0);

        // ---- Gtail (32 cols) ----
        float psv0 = ps[n * 2], psv1 = ps[n * 2 + 1];
        float e = cS > 0 ? 1.f : 0.f;
        float fcA = (float)cA;
        float v = 0.f;
        if (lane == 0)       v = psv0;
        else if (lane == 1)  v = psv1;
        else if (lane < 18)  v = us;
        else if (lane < 20)  v = pas;
        else if (lane == 20) v = sumDisA;
        else if (lane == 21) v = fcA * psv0;
        else if (lane == 22) v = fcA * psv1;
        else if (lane == 23) v = fcA;
        else if (lane == 24) v = e * psv0;
        else if (lane == 25) v = e * psv1;
        else if (lane == 26) v = e;
        else if (lane == 27) v = invd * sumDisS;
        else if (lane == 28) v = 1.f;
        if (lane < 32) Gtail[(size_t)n * 32 + lane] = v;
    }
}

// ---------------- K4: final GEMM via fp16 MFMA: out = [h|x|Gtail] @ WG + aggPXs ----------------
__global__ __launch_bounds__(256) void gemmF_kernel(const float* __restrict__ h,
                                                    const float* __restrict__ x,
                                                    const float* __restrict__ Gtail,
                                                    const _Float16* __restrict__ WGh,
                                                    const float* __restrict__ aggPXs,
                                                    float* __restrict__ C) {
    int wid = threadIdx.x >> 6, lane = threadIdx.x & 63;
    int mt = blockIdx.x * 4 + wid;           // 16-row tile id
    int row0 = mt * 16;
    int arow = row0 + (lane & 15);
    if (arow >= N_S) arow = N_S - 1;         // clamp; stores guarded below
    int kh = (lane >> 4) * 8;                // k offset within each 32-block

    const float* hp = h + (size_t)arow * HID;
    const float* xp = x + (size_t)arow * XD;
    const float* gp = Gtail + (size_t)arow * 32;

    f16x8 afrag[6];
#pragma unroll
    for (int kb = 0; kb < 6; ++kb) {
        int k = kb * 32 + kh;
        const float* src;
        if (k < 128)      src = hp + k;
        else if (k < 160) src = xp + (k - 128);
        else              src = gp + (k - 160);
        float4 lo = *(const float4*)(src);
        float4 hi = *(const float4*)(src + 4);
        f16x8 a;
        a[0] = (_Float16)lo.x; a[1] = (_Float16)lo.y;
        a[2] = (_Float16)lo.z; a[3] = (_Float16)lo.w;
        a[4] = (_Float16)hi.x; a[5] = (_Float16)hi.y;
        a[6] = (_Float16)hi.z; a[7] = (_Float16)hi.w;
        afrag[kb] = a;
    }

    const f16x8* Bf = (const f16x8*)WGh;     // [(kb*8+nt)*64 + lane]
#pragma unroll
    for (int nt = 0; nt < 8; ++nt) {
        f32x4 acc = {0.f, 0.f, 0.f, 0.f};
#pragma unroll
        for (int kb = 0; kb < 6; ++kb) {
            f16x8 bfr = Bf[(size_t)(kb * 8 + nt) * 64 + lane];
            acc = __builtin_amdgcn_mfma_f32_16x16x32_f16(afrag[kb], bfr, acc, 0, 0, 0);
        }
        int col = nt * 16 + (lane & 15);
        int rbase = row0 + (lane >> 4) * 4;
#pragma unroll
        for (int i = 0; i < 4; ++i) {
            int gr = rbase + i;
            if (gr < N_S) {
                C[(size_t)gr * HID + col] =
                    acc[i] + aggPXs[(size_t)gr * HID + col];
            }
        }
    }
}

extern "C" void kernel_launch(void* const* d_in, const int* in_sizes, int n_in,
                              void* d_out, int out_size, void* d_ws, size_t ws_size,
                              hipStream_t stream) {
    const float* h     = (const float*)d_in[0];
    const float* x     = (const float*)d_in[1];
    const float* u     = (const float*)d_in[2];
    const float* ps    = (const float*)d_in[3];
    const float* pa    = (const float*)d_in[4];
    const float* dis_a = (const float*)d_in[5];
    const float* dis_s = (const float*)d_in[6];
    const int* a2s_src = (const int*)d_in[7];
    const int* a2s_dst = (const int*)d_in[8];
    const int* s2s_src = (const int*)d_in[9];
    const int* s2s_dst = (const int*)d_in[10];
    const float* Wu2h  = (const float*)d_in[11];
    const float* bu2h  = (const float*)d_in[12];
    const float* Wx2h  = (const float*)d_in[13];
    const float* bx2h  = (const float*)d_in[14];
    const float* Wupd  = (const float*)d_in[15];
    const float* bupd  = (const float*)d_in[16];
    float* out = (float*)d_out;

    // Workspace layout (~61 MB total):
    char* ws = (char*)d_ws;
    unsigned* bktCnt = (unsigned*)(ws + 0);                       // 392 u32 (pad 4096)
    unsigned long long* bktS = (unsigned long long*)(ws + 4096);  // 196*5120*8 = 8,028,160
    unsigned long long* bktA = (unsigned long long*)(ws + 8032256);
    __half* PX    = (__half*)(ws + 16060416);                     // 12.8 MB
    float* aggPXs = (float*)(ws + 28860416);                      // 25.6 MB
    float* Gtail  = (float*)(ws + 54460416);                      // 6.4 MB
    float* WXsrc  = (float*)(ws + 60860416);                      // 90,112 B
    _Float16* WGh = (_Float16*)(ws + 60950528);                   // 49,152 B

    // K1: zero bucket counters + build WXsrc/WGh
    prep_kernel<<<196, 256, 0, stream>>>(Wu2h, bu2h, Wx2h, bx2h, Wupd, bupd,
                                         WXsrc, WGh, bktCnt);

    // K2: projX (blocks 0..781) overlapped with edge binning (blocks 782..1563)
    phase1_kernel<<<PROJ_NB + 2 * BIN_NB, 256, 0, stream>>>(
        x, h, ps, WXsrc, PX,
        s2s_src, s2s_dst, dis_s, a2s_src, a2s_dst, dis_a,
        bktCnt, bktS, bktA);

    // K3: per-bucket CSR build in LDS + aggregate
    s2_kernel<<<NBKT * 4, 256, 0, stream>>>(
        ps, u, pa, (const __half2*)PX,
        bktCnt, bktS, bktA, aggPXs, Gtail);

    // K4: final GEMM (MFMA fp16)
    gemmF_kernel<<<PROJ_NB, 256, 0, stream>>>(h, x, Gtail, WGh, aggPXs, out);
}

// Round 6
// 256.936 us; speedup vs baseline: 1.2908x; 1.0855x over previous
//
#include <hip/hip_runtime.h>
#include <hip/hip_fp16.h>

#define N_S 50000
#define N_A 50000
#define E_A 800000
#define E_S 800000
#define HID 128
#define XD 32
#define UD 16

#define KF_PX 176    // projX virtual K: [x32 | h128 | ps2 | pad14]
#define KF_G 192     // final virtual K: [h128 | x32 | tail32]
#define DISQ 65535.0f

#define NBKT 196     // dst buckets of 256 nodes (dst>>8)
#define CAPB 5120    // records per bucket (mean 4082, +16 sigma)
#define CAPN 48      // per-node list cap (deg ~Poisson(16), max ~38)
#define NPB 64       // nodes per s2 block

#define BM 64
#define BK 16
#define EPT 8        // edges per bin thread
#define PROJ_NB ((N_S + BM - 1) / BM)                    // 782
#define BIN_NB ((E_S + 256 * EPT - 1) / (256 * EPT))     // 391 per graph

typedef _Float16 f16x8 __attribute__((ext_vector_type(8)));
typedef float f32x4 __attribute__((ext_vector_type(4)));

// ---------------- K1: zero bucket counters + build fused weights ----------------
// WGh in MFMA B-frag order: WGh[((kb*8+nt)*64 + lane)*8 + j]
//   = WG_true[32*kb + (lane>>4)*8 + j][16*nt + (lane&15)]  (fp16)
__global__ void prep_kernel(const float* __restrict__ Wu2h, const float* __restrict__ bu2h,
                            const float* __restrict__ Wx2h, const float* __restrict__ bx2h,
                            const float* __restrict__ Wupd, const float* __restrict__ bupd,
                            float* __restrict__ WXsrc, _Float16* __restrict__ WGh,
                            unsigned* __restrict__ bktCnt) {
    int idx = blockIdx.x * blockDim.x + threadIdx.x;
    if (idx < 2 * NBKT) bktCnt[idx] = 0u;
    if (idx >= (KF_PX + KF_G) * HID) return;
    int r = idx >> 7, j = idx & 127;
    if (r < KF_PX) {
        float v = 0.f;
        if (r < 162) {
            const float* a = Wx2h + (size_t)r * HID;
            float acc = 0.f;
            for (int k = 0; k < HID; ++k) acc += a[k] * Wupd[(258 + k) * HID + j];
            v = acc;
        }
        WXsrc[(size_t)r * HID + j] = v;
        return;
    }
    r -= KF_PX;
    float v = 0.f;
    if (r < 128) {
        v = Wupd[(2 + r) * HID + j];
    } else if (r < 160) {
        v = Wupd[(386 + r - 128) * HID + j];
    } else if (r < 162) {
        v = Wupd[(r - 160) * HID + j];
    } else if (r < 184) {
        const float* a;
        if (r < 180)      a = Wu2h + (size_t)(r - 162) * HID;
        else if (r == 180) a = Wu2h + (size_t)20 * HID;
        else if (r < 183)  a = Wu2h + (size_t)(18 + r - 181) * HID;
        else               a = bu2h;
        float acc = 0.f;
        for (int k = 0; k < HID; ++k) acc += a[k] * Wupd[(130 + k) * HID + j];
        v = acc;
    } else if (r < 188) {
        const float* a;
        if (r < 186)      a = Wx2h + (size_t)(162 + r - 184) * HID;
        else if (r == 186) a = bx2h;
        else               a = Wx2h + (size_t)164 * HID;
        float acc = 0.f;
        for (int k = 0; k < HID; ++k) acc += a[k] * Wupd[(258 + k) * HID + j];
        v = acc;
    } else if (r == 188) {
        v = bupd[j];
    }
    int kb = r >> 5, rr = r & 31;
    int lanehi = rr >> 3, j8 = rr & 7;
    int nt = j >> 4, lanelo = j & 15;
    size_t off = (((size_t)(kb * 8 + nt) * 64) + lanehi * 16 + lanelo) * 8 + j8;
    WGh[off] = (_Float16)v;
}

// ---------------- K2: projX GEMM (blocks 0..781) + edge binning (blocks 782..1563) -------
__global__ __launch_bounds__(256) void phase1_kernel(
        const float* __restrict__ x, const float* __restrict__ h, const float* __restrict__ ps,
        const float* __restrict__ WXsrc, __half* __restrict__ PX,
        const int* __restrict__ srcS, const int* __restrict__ dstS, const float* __restrict__ disS,
        const int* __restrict__ srcA, const int* __restrict__ dstA, const float* __restrict__ disA,
        unsigned* __restrict__ bktCnt,
        unsigned long long* __restrict__ bktS, unsigned long long* __restrict__ bktA) {
    __shared__ unsigned long long sbuf[2432];   // 19456 B, unioned between paths
    int tid = threadIdx.x;

    if (blockIdx.x >= PROJ_NB) {
        int bid2 = blockIdx.x - PROJ_NB;
        const int* src; const int* dst; const float* dis;
        unsigned long long* bkt; unsigned* bcnt; int nE, base;
        if (bid2 < BIN_NB) {
            src = srcS; dst = dstS; dis = disS; bkt = bktS; bcnt = bktCnt;
            nE = E_S; base = bid2 * (256 * EPT);
        } else {
            src = srcA; dst = dstA; dis = disA; bkt = bktA; bcnt = bktCnt + NBKT;
            nE = E_A; base = (bid2 - BIN_NB) * (256 * EPT);
        }
        unsigned long long* recs = sbuf;                 // 2048 records
        unsigned* hist  = (unsigned*)(sbuf + 2048);      // 256
        unsigned* scan  = hist + 256;                    // 256
        unsigned* gbase = hist + 512;                    // 256

        hist[tid] = 0u;
        __syncthreads();

        unsigned long long rec[EPT]; int bk[EPT]; unsigned rank[EPT];
#pragma unroll
        for (int r = 0; r < EPT; ++r) {
            int t = base + r * 256 + tid;
            bool ok = t < nE;
            int tt = ok ? t : 0;
            int s = __builtin_nontemporal_load(src + tt);
            int d = __builtin_nontemporal_load(dst + tt);
            float f = __builtin_nontemporal_load(dis + tt);
            unsigned disq = (unsigned)(f * DISQ + 0.5f);
            bk[r] = ok ? (d >> 8) : -1;
            rec[r] = ((unsigned long long)(d >> 8) << 48) |
                     ((unsigned long long)disq << 24) |
                     ((unsigned long long)(unsigned)s << 8) |
                     (unsigned long long)(d & 255);
        }
#pragma unroll
        for (int r = 0; r < EPT; ++r)
            if (bk[r] >= 0) rank[r] = atomicAdd(&hist[bk[r]], 1u);
        __syncthreads();

        // inclusive scan of hist -> scan
        scan[tid] = hist[tid];
        __syncthreads();
        for (int off = 1; off < 256; off <<= 1) {
            unsigned v = scan[tid];
            unsigned add = (tid >= off) ? scan[tid - off] : 0u;
            __syncthreads();
            scan[tid] = v + add;
            __syncthreads();
        }

        // stage records LDS-ordered by bucket
#pragma unroll
        for (int r = 0; r < EPT; ++r) {
            if (bk[r] >= 0) {
                unsigned pos = scan[bk[r]] - hist[bk[r]] + rank[r];
                recs[pos] = rec[r];
            }
        }
        // reserve global space per bucket
        if (tid < NBKT) {
            unsigned c = hist[tid];
            gbase[tid] = c ? atomicAdd(&bcnt[tid], c) : 0u;
        }
        __syncthreads();

        int total = (int)scan[255];
        for (int p = tid; p < total; p += 256) {
            unsigned long long rr = recs[p];
            int bb = (int)(rr >> 48);
            unsigned gi = gbase[bb] + (unsigned)p - (scan[bb] - hist[bb]);
            if (gi < CAPB) bkt[(size_t)bb * CAPB + gi] = rr;
        }
        return;
    }

    // ---- projX: PX[N_S x 128] (fp16) = [x|h|ps] @ WXsrc ----
    float* As = (float*)sbuf;            // [BK][BM]
    float* Bs = As + BK * BM;            // [BK][HID]
    int m0 = blockIdx.x * BM;
    int tm = tid >> 5, tn = tid & 31;
    float acc[8][4] = {};
    int la_m = tid >> 2;
    int la_k = (tid & 3) * 4;
    for (int kc = 0; kc < KF_PX; kc += BK) {
        int gm = m0 + la_m;
        int k = kc + la_k;
        float4 av = make_float4(0.f, 0.f, 0.f, 0.f);
        if (gm < N_S) {
            if (k < 32)        av = *(const float4*)(x + (size_t)gm * XD + k);
            else if (k < 160)  av = *(const float4*)(h + (size_t)gm * HID + (k - 32));
            else if (k == 160) av = make_float4(ps[gm * 2], ps[gm * 2 + 1], 0.f, 0.f);
        }
        As[(la_k + 0) * BM + la_m] = av.x;
        As[(la_k + 1) * BM + la_m] = av.y;
        As[(la_k + 2) * BM + la_m] = av.z;
        As[(la_k + 3) * BM + la_m] = av.w;
#pragma unroll
        for (int t2 = 0; t2 < 2; ++t2) {
            int i = tid * 2 + t2;
            int bkk = i >> 5, bn = (i & 31) * 4;
            *(float4*)&Bs[bkk * HID + bn] = *(const float4*)(WXsrc + (size_t)(kc + bkk) * HID + bn);
        }
        __syncthreads();
#pragma unroll
        for (int k2 = 0; k2 < BK; ++k2) {
            float4 a0 = *(float4*)&As[k2 * BM + tm * 8];
            float4 a1 = *(float4*)&As[k2 * BM + tm * 8 + 4];
            float4 b0 = *(float4*)&Bs[k2 * HID + tn * 4];
            float am[8] = {a0.x, a0.y, a0.z, a0.w, a1.x, a1.y, a1.z, a1.w};
            float bv[4] = {b0.x, b0.y, b0.z, b0.w};
#pragma unroll
            for (int i = 0; i < 8; ++i)
#pragma unroll
                for (int j = 0; j < 4; ++j)
                    acc[i][j] += am[i] * bv[j];
        }
        __syncthreads();
    }
    for (int i = 0; i < 8; ++i) {
        int gm = m0 + tm * 8 + i;
        if (gm < N_S) {
            __half2* row = (__half2*)(PX + (size_t)gm * HID);
            row[tn * 2]     = __floats2half2_rn(acc[i][0], acc[i][1]);
            row[tn * 2 + 1] = __floats2half2_rn(acc[i][2], acc[i][3]);
        }
    }
}

// ---------------- K3: per-bucket LDS CSR build + aggregate ----------------
// 512 threads = 8 waves; block = (bucket, 64-node subrange); each wave aggregates 8 nodes.
__global__ __launch_bounds__(512) void s2_kernel(
        const float* __restrict__ ps, const float* __restrict__ u, const float* __restrict__ pa,
        const __half2* __restrict__ PX2,
        const unsigned* __restrict__ bktCnt,
        const unsigned long long* __restrict__ bktS, const unsigned long long* __restrict__ bktA,
        float* __restrict__ aggPXs, float* __restrict__ Gtail) {
    int b = blockIdx.x >> 2, sub = blockIdx.x & 3;
    int n0 = b * 256 + sub * 64;
    if (n0 >= N_S) return;
    int tid = threadIdx.x;

    __shared__ unsigned listS[NPB * CAPN];   // 12 KB
    __shared__ unsigned listA[NPB * CAPN];   // 12 KB
    __shared__ unsigned cntL[2][NPB];
    __shared__ unsigned disL[2][NPB];

    if (tid < 128) {
        cntL[tid >> 6][tid & 63] = 0u;
        disL[tid >> 6][tid & 63] = 0u;
    }
    __syncthreads();

    for (int g = 0; g < 2; ++g) {
        const unsigned long long* bp = (g ? bktA : bktS) + (size_t)b * CAPB;
        unsigned cnt = bktCnt[g * NBKT + b];
        if (cnt > CAPB) cnt = CAPB;
        for (unsigned e = tid; e < cnt; e += 512) {
            unsigned long long rr = bp[e];
            int dl = (int)(rr & 255);
            if ((dl >> 6) == sub) {
                int l = dl & 63;
                unsigned disq = (unsigned)((rr >> 24) & 0xFFFF);
                unsigned w = (disq << 16) | (unsigned)((rr >> 8) & 0xFFFF);
                unsigned rk = atomicAdd(&cntL[g][l], 1u);
                atomicAdd(&disL[g][l], disq);
                if (rk < CAPN) {
                    if (g) listA[l * CAPN + rk] = w;
                    else   listS[l * CAPN + rk] = w;
                }
            }
        }
    }
    __syncthreads();

    int wv = tid >> 6, lane = tid & 63;
    for (int i = 0; i < 8; ++i) {
        int l = wv * 8 + i;
        int n = n0 + l;
        if (n >= N_S) break;
        int cS = (int)cntL[0][l];
        int cA = (int)cntL[1][l];
        float sumDisS = (float)disL[0][l] * (1.0f / DISQ);
        float sumDisA = (float)disL[1][l] * (1.0f / DISQ);
        int cSc = cS < CAPN ? cS : CAPN;
        int cAc = cA < CAPN ? cA : CAPN;

        unsigned mywS = (lane < cSc) ? listS[l * CAPN + lane] : 0u;
        unsigned mywA = (lane < cAc) ? listA[l * CAPN + lane] : 0u;

        // ---- s2s: sum projected fp16 rows, 8-deep independent load batches ----
        int myidxS = (int)(mywS & 0xFFFFu);
        float ax = 0.f, ay = 0.f;
        int rounds = (cSc + 7) & ~7;
        for (int j = 0; j < rounds; j += 8) {
            float2 f[8];
            float w[8];
#pragma unroll
            for (int t = 0; t < 8; ++t) {
                int jj = j + t;
                int s = __shfl(myidxS, jj);
                f[t] = __half22float2(PX2[(size_t)s * 64 + lane]);
                w[t] = (jj < cSc) ? 1.f : 0.f;
            }
#pragma unroll
            for (int t = 0; t < 8; ++t) {
                ax += w[t] * f[t].x;
                ay += w[t] * f[t].y;
            }
        }
        float invd = cS > 0 ? 1.f / (float)cS : 0.f;
        *(float2*)(aggPXs + (size_t)n * HID + lane * 2) = make_float2(ax * invd, ay * invd);

        // ---- a2s: raw [u16 | pa2] sums; 4 lane-groups, 8 edges in flight ----
        int g2 = lane >> 4, ll = lane & 15;
        int myidxA = (int)(mywA & 0xFFFFu);
        float uacc = 0.f, paacc = 0.f;
        int iters = (cAc + 7) >> 3;
        for (int it = 0; it < iters; ++it) {
            int jj0 = it * 8 + g2;
            int jj1 = jj0 + 4;
            int s0 = __shfl(myidxA, jj0 < 64 ? jj0 : 0);
            int s1 = __shfl(myidxA, jj1 < 64 ? jj1 : 0);
            float w0 = (jj0 < cAc) ? 1.f : 0.f;
            float w1 = (jj1 < cAc) ? 1.f : 0.f;
            float u0 = u[(size_t)s0 * UD + ll];
            float u1 = u[(size_t)s1 * UD + ll];
            float p0 = 0.f, p1 = 0.f;
            if (ll < 2) {
                p0 = pa[s0 * 2 + ll];
                p1 = pa[s1 * 2 + ll];
            }
            uacc += w0 * u0 + w1 * u1;
            if (ll < 2) paacc += w0 * p0 + w1 * p1;
        }
        uacc += __shfl_xor(uacc, 16);
        uacc += __shfl_xor(uacc, 32);
        paacc += __shfl_xor(paacc, 16);
        paacc += __shfl_xor(paacc, 32);
        float us  = __shfl(uacc, (lane >= 2 && lane < 18) ? lane - 2 : 0);
        float pas = __shfl(paacc, (lane >= 18 && lane < 20) ? lane - 18 : 0);

        // ---- Gtail (32 cols) ----
        float psv0 = ps[n * 2], psv1 = ps[n * 2 + 1];
        float e = cS > 0 ? 1.f : 0.f;
        float fcA = (float)cA;
        float v = 0.f;
        if (lane == 0)       v = psv0;
        else if (lane == 1)  v = psv1;
        else if (lane < 18)  v = us;
        else if (lane < 20)  v = pas;
        else if (lane == 20) v = sumDisA;
        else if (lane == 21) v = fcA * psv0;
        else if (lane == 22) v = fcA * psv1;
        else if (lane == 23) v = fcA;
        else if (lane == 24) v = e * psv0;
        else if (lane == 25) v = e * psv1;
        else if (lane == 26) v = e;
        else if (lane == 27) v = invd * sumDisS;
        else if (lane == 28) v = 1.f;
        if (lane < 32) Gtail[(size_t)n * 32 + lane] = v;
    }
}

// ---------------- K4: final GEMM via fp16 MFMA: out = [h|x|Gtail] @ WG + aggPXs ----------------
__global__ __launch_bounds__(256) void gemmF_kernel(const float* __restrict__ h,
                                                    const float* __restrict__ x,
                                                    const float* __restrict__ Gtail,
                                                    const _Float16* __restrict__ WGh,
                                                    const float* __restrict__ aggPXs,
                                                    float* __restrict__ C) {
    int wid = threadIdx.x >> 6, lane = threadIdx.x & 63;
    int mt = blockIdx.x * 4 + wid;           // 16-row tile id
    int row0 = mt * 16;
    int arow = row0 + (lane & 15);
    if (arow >= N_S) arow = N_S - 1;         // clamp; stores guarded below
    int kh = (lane >> 4) * 8;                // k offset within each 32-block

    const float* hp = h + (size_t)arow * HID;
    const float* xp = x + (size_t)arow * XD;
    const float* gp = Gtail + (size_t)arow * 32;

    f16x8 afrag[6];
#pragma unroll
    for (int kb = 0; kb < 6; ++kb) {
        int k = kb * 32 + kh;
        const float* src;
        if (k < 128)      src = hp + k;
        else if (k < 160) src = xp + (k - 128);
        else              src = gp + (k - 160);
        float4 lo = *(const float4*)(src);
        float4 hi = *(const float4*)(src + 4);
        f16x8 a;
        a[0] = (_Float16)lo.x; a[1] = (_Float16)lo.y;
        a[2] = (_Float16)lo.z; a[3] = (_Float16)lo.w;
        a[4] = (_Float16)hi.x; a[5] = (_Float16)hi.y;
        a[6] = (_Float16)hi.z; a[7] = (_Float16)hi.w;
        afrag[kb] = a;
    }

    const f16x8* Bf = (const f16x8*)WGh;     // [(kb*8+nt)*64 + lane]
#pragma unroll
    for (int nt = 0; nt < 8; ++nt) {
        f32x4 acc = {0.f, 0.f, 0.f, 0.f};
#pragma unroll
        for (int kb = 0; kb < 6; ++kb) {
            f16x8 bfr = Bf[(size_t)(kb * 8 + nt) * 64 + lane];
            acc = __builtin_amdgcn_mfma_f32_16x16x32_f16(afrag[kb], bfr, acc, 0, 0, 0);
        }
        int col = nt * 16 + (lane & 15);
        int rbase = row0 + (lane >> 4) * 4;
#pragma unroll
        for (int i = 0; i < 4; ++i) {
            int gr = rbase + i;
            if (gr < N_S) {
                C[(size_t)gr * HID + col] =
                    acc[i] + aggPXs[(size_t)gr * HID + col];
            }
        }
    }
}

extern "C" void kernel_launch(void* const* d_in, const int* in_sizes, int n_in,
                              void* d_out, int out_size, void* d_ws, size_t ws_size,
                              hipStream_t stream) {
    const float* h     = (const float*)d_in[0];
    const float* x     = (const float*)d_in[1];
    const float* u     = (const float*)d_in[2];
    const float* ps    = (const float*)d_in[3];
    const float* pa    = (const float*)d_in[4];
    const float* dis_a = (const float*)d_in[5];
    const float* dis_s = (const float*)d_in[6];
    const int* a2s_src = (const int*)d_in[7];
    const int* a2s_dst = (const int*)d_in[8];
    const int* s2s_src = (const int*)d_in[9];
    const int* s2s_dst = (const int*)d_in[10];
    const float* Wu2h  = (const float*)d_in[11];
    const float* bu2h  = (const float*)d_in[12];
    const float* Wx2h  = (const float*)d_in[13];
    const float* bx2h  = (const float*)d_in[14];
    const float* Wupd  = (const float*)d_in[15];
    const float* bupd  = (const float*)d_in[16];
    float* out = (float*)d_out;

    // Workspace layout (~61 MB total):
    char* ws = (char*)d_ws;
    unsigned* bktCnt = (unsigned*)(ws + 0);                       // 392 u32 (pad 4096)
    unsigned long long* bktS = (unsigned long long*)(ws + 4096);  // 196*5120*8 = 8,028,160
    unsigned long long* bktA = (unsigned long long*)(ws + 8032256);
    __half* PX    = (__half*)(ws + 16060416);                     // 12.8 MB
    float* aggPXs = (float*)(ws + 28860416);                      // 25.6 MB
    float* Gtail  = (float*)(ws + 54460416);                      // 6.4 MB
    float* WXsrc  = (float*)(ws + 60860416);                      // 90,112 B
    _Float16* WGh = (_Float16*)(ws + 60950528);                   // 49,152 B

    // K1: zero bucket counters + build WXsrc/WGh
    prep_kernel<<<196, 256, 0, stream>>>(Wu2h, bu2h, Wx2h, bx2h, Wupd, bupd,
                                         WXsrc, WGh, bktCnt);

    // K2: projX (blocks 0..781) overlapped with edge binning (blocks 782..1563)
    phase1_kernel<<<PROJ_NB + 2 * BIN_NB, 256, 0, stream>>>(
        x, h, ps, WXsrc, PX,
        s2s_src, s2s_dst, dis_s, a2s_src, a2s_dst, dis_a,
        bktCnt, bktS, bktA);

    // K3: per-bucket CSR build in LDS + aggregate (512 thr = 8 waves, 8 nodes/wave)
    s2_kernel<<<NBKT * 4, 512, 0, stream>>>(
        ps, u, pa, (const __half2*)PX,
        bktCnt, bktS, bktA, aggPXs, Gtail);

    // K4: final GEMM (MFMA fp16)
    gemmF_kernel<<<PROJ_NB, 256, 0, stream>>>(h, x, Gtail, WGh, aggPXs, out);
}

// Round 8
// 248.212 us; speedup vs baseline: 1.3362x; 1.0351x over previous
//
#include <hip/hip_runtime.h>
#include <hip/hip_fp16.h>

#define N_S 50000
#define N_A 50000
#define E_A 800000
#define E_S 800000
#define HID 128
#define XD 32
#define UD 16

#define KF_PX 176    // projX virtual K: [x32 | h128 | ps2 | pad14]
#define KF_G 192     // final virtual K: [h128 | x32 | tail32]
#define DISQ 65535.0f

#define NBKT 196     // dst buckets of 256 nodes (dst>>8)  -- PROVEN round-6 binning
#define CAPB 5120    // records per bucket (mean 4082, +16 sigma)
#define CAPN 48      // per-node list cap (deg ~Poisson(16), max ~38)

#define BM 64
#define BK 16
#define EPT 8        // edges per bin thread
#define PROJ_NB ((N_S + BM - 1) / BM)                    // 782
#define BIN_NB ((E_S + 256 * EPT - 1) / (256 * EPT))     // 391 per graph

typedef _Float16 f16x8 __attribute__((ext_vector_type(8)));
typedef float f32x4 __attribute__((ext_vector_type(4)));

// ---------------- K1: zero bucket counters + build fused weights ----------------
// WGh in MFMA B-frag order: WGh[((kb*8+nt)*64 + lane)*8 + j]
//   = WG_true[32*kb + (lane>>4)*8 + j][16*nt + (lane&15)]  (fp16)
__global__ void prep_kernel(const float* __restrict__ Wu2h, const float* __restrict__ bu2h,
                            const float* __restrict__ Wx2h, const float* __restrict__ bx2h,
                            const float* __restrict__ Wupd, const float* __restrict__ bupd,
                            float* __restrict__ WXsrc, _Float16* __restrict__ WGh,
                            unsigned* __restrict__ bktCnt) {
    int idx = blockIdx.x * blockDim.x + threadIdx.x;
    if (idx < 2 * NBKT) bktCnt[idx] = 0u;
    if (idx >= (KF_PX + KF_G) * HID) return;
    int r = idx >> 7, j = idx & 127;
    if (r < KF_PX) {
        float v = 0.f;
        if (r < 162) {
            const float* a = Wx2h + (size_t)r * HID;
            float acc = 0.f;
            for (int k = 0; k < HID; ++k) acc += a[k] * Wupd[(258 + k) * HID + j];
            v = acc;
        }
        WXsrc[(size_t)r * HID + j] = v;
        return;
    }
    r -= KF_PX;
    float v = 0.f;
    if (r < 128) {
        v = Wupd[(2 + r) * HID + j];
    } else if (r < 160) {
        v = Wupd[(386 + r - 128) * HID + j];
    } else if (r < 162) {
        v = Wupd[(r - 160) * HID + j];
    } else if (r < 184) {
        const float* a;
        if (r < 180)      a = Wu2h + (size_t)(r - 162) * HID;
        else if (r == 180) a = Wu2h + (size_t)20 * HID;
        else if (r < 183)  a = Wu2h + (size_t)(18 + r - 181) * HID;
        else               a = bu2h;
        float acc = 0.f;
        for (int k = 0; k < HID; ++k) acc += a[k] * Wupd[(130 + k) * HID + j];
        v = acc;
    } else if (r < 188) {
        const float* a;
        if (r < 186)      a = Wx2h + (size_t)(162 + r - 184) * HID;
        else if (r == 186) a = bx2h;
        else               a = Wx2h + (size_t)164 * HID;
        float acc = 0.f;
        for (int k = 0; k < HID; ++k) acc += a[k] * Wupd[(258 + k) * HID + j];
        v = acc;
    } else if (r == 188) {
        v = bupd[j];
    }
    int kb = r >> 5, rr = r & 31;
    int lanehi = rr >> 3, j8 = rr & 7;
    int nt = j >> 4, lanelo = j & 15;
    size_t off = (((size_t)(kb * 8 + nt) * 64) + lanehi * 16 + lanelo) * 8 + j8;
    WGh[off] = (_Float16)v;
}

// ---------------- K2: projX GEMM (blocks 0..781) + edge binning (blocks 782..1563) -------
// bin: record = (bucket<<48)|(disq<<24)|(src<<8)|dstLocal8; LDS-hist + LDS-ordered staging,
// one global atomic per (block,bucket), ~coalesced 8B-record segment flush. [round-6 proven]
__global__ __launch_bounds__(256) void phase1_kernel(
        const float* __restrict__ x, const float* __restrict__ h, const float* __restrict__ ps,
        const float* __restrict__ WXsrc, __half* __restrict__ PX,
        const int* __restrict__ srcS, const int* __restrict__ dstS, const float* __restrict__ disS,
        const int* __restrict__ srcA, const int* __restrict__ dstA, const float* __restrict__ disA,
        unsigned* __restrict__ bktCnt,
        unsigned long long* __restrict__ bktS, unsigned long long* __restrict__ bktA) {
    __shared__ unsigned long long sbuf[2432];   // 19456 B, unioned between paths
    int tid = threadIdx.x;

    if (blockIdx.x >= PROJ_NB) {
        int bid2 = blockIdx.x - PROJ_NB;
        const int* src; const int* dst; const float* dis;
        unsigned long long* bkt; unsigned* bcnt; int nE, base;
        if (bid2 < BIN_NB) {
            src = srcS; dst = dstS; dis = disS; bkt = bktS; bcnt = bktCnt;
            nE = E_S; base = bid2 * (256 * EPT);
        } else {
            src = srcA; dst = dstA; dis = disA; bkt = bktA; bcnt = bktCnt + NBKT;
            nE = E_A; base = (bid2 - BIN_NB) * (256 * EPT);
        }
        unsigned long long* recs = sbuf;                 // 2048 records
        unsigned* hist  = (unsigned*)(sbuf + 2048);      // 256
        unsigned* scan  = hist + 256;                    // 256
        unsigned* gbase = hist + 512;                    // 256

        hist[tid] = 0u;
        __syncthreads();

        unsigned long long rec[EPT]; int bk[EPT]; unsigned rank[EPT];
#pragma unroll
        for (int r = 0; r < EPT; ++r) {
            int t = base + r * 256 + tid;
            bool ok = t < nE;
            int tt = ok ? t : 0;
            int s = __builtin_nontemporal_load(src + tt);
            int d = __builtin_nontemporal_load(dst + tt);
            float f = __builtin_nontemporal_load(dis + tt);
            unsigned disq = (unsigned)(f * DISQ + 0.5f);
            bk[r] = ok ? (d >> 8) : -1;
            rec[r] = ((unsigned long long)(d >> 8) << 48) |
                     ((unsigned long long)disq << 24) |
                     ((unsigned long long)(unsigned)s << 8) |
                     (unsigned long long)(d & 255);
        }
#pragma unroll
        for (int r = 0; r < EPT; ++r)
            if (bk[r] >= 0) rank[r] = atomicAdd(&hist[bk[r]], 1u);
        __syncthreads();

        // inclusive scan of hist -> scan
        scan[tid] = hist[tid];
        __syncthreads();
        for (int off = 1; off < 256; off <<= 1) {
            unsigned v = scan[tid];
            unsigned add = (tid >= off) ? scan[tid - off] : 0u;
            __syncthreads();
            scan[tid] = v + add;
            __syncthreads();
        }

        // stage records LDS-ordered by bucket
#pragma unroll
        for (int r = 0; r < EPT; ++r) {
            if (bk[r] >= 0) {
                unsigned pos = scan[bk[r]] - hist[bk[r]] + rank[r];
                recs[pos] = rec[r];
            }
        }
        // reserve global space per bucket
        if (tid < NBKT) {
            unsigned c = hist[tid];
            gbase[tid] = c ? atomicAdd(&bcnt[tid], c) : 0u;
        }
        __syncthreads();

        int total = (int)scan[255];
        for (int p = tid; p < total; p += 256) {
            unsigned long long rr = recs[p];
            int bb = (int)(rr >> 48);
            unsigned gi = gbase[bb] + (unsigned)p - (scan[bb] - hist[bb]);
            if (gi < CAPB) bkt[(size_t)bb * CAPB + gi] = rr;
        }
        return;
    }

    // ---- projX: PX[N_S x 128] (fp16) = [x|h|ps] @ WXsrc ----
    float* As = (float*)sbuf;            // [BK][BM]
    float* Bs = As + BK * BM;            // [BK][HID]
    int m0 = blockIdx.x * BM;
    int tm = tid >> 5, tn = tid & 31;
    float acc[8][4] = {};
    int la_m = tid >> 2;
    int la_k = (tid & 3) * 4;
    for (int kc = 0; kc < KF_PX; kc += BK) {
        int gm = m0 + la_m;
        int k = kc + la_k;
        float4 av = make_float4(0.f, 0.f, 0.f, 0.f);
        if (gm < N_S) {
            if (k < 32)        av = *(const float4*)(x + (size_t)gm * XD + k);
            else if (k < 160)  av = *(const float4*)(h + (size_t)gm * HID + (k - 32));
            else if (k == 160) av = make_float4(ps[gm * 2], ps[gm * 2 + 1], 0.f, 0.f);
        }
        As[(la_k + 0) * BM + la_m] = av.x;
        As[(la_k + 1) * BM + la_m] = av.y;
        As[(la_k + 2) * BM + la_m] = av.z;
        As[(la_k + 3) * BM + la_m] = av.w;
#pragma unroll
        for (int t2 = 0; t2 < 2; ++t2) {
            int i = tid * 2 + t2;
            int bkk = i >> 5, bn = (i & 31) * 4;
            *(float4*)&Bs[bkk * HID + bn] = *(const float4*)(WXsrc + (size_t)(kc + bkk) * HID + bn);
        }
        __syncthreads();
#pragma unroll
        for (int k2 = 0; k2 < BK; ++k2) {
            float4 a0 = *(float4*)&As[k2 * BM + tm * 8];
            float4 a1 = *(float4*)&As[k2 * BM + tm * 8 + 4];
            float4 b0 = *(float4*)&Bs[k2 * HID + tn * 4];
            float am[8] = {a0.x, a0.y, a0.z, a0.w, a1.x, a1.y, a1.z, a1.w};
            float bv[4] = {b0.x, b0.y, b0.z, b0.w};
#pragma unroll
            for (int i = 0; i < 8; ++i)
#pragma unroll
                for (int j = 0; j < 4; ++j)
                    acc[i][j] += am[i] * bv[j];
        }
        __syncthreads();
    }
    for (int i = 0; i < 8; ++i) {
        int gm = m0 + tm * 8 + i;
        if (gm < N_S) {
            __half2* row = (__half2*)(PX + (size_t)gm * HID);
            row[tn * 2]     = __floats2half2_rn(acc[i][0], acc[i][1]);
            row[tn * 2 + 1] = __floats2half2_rn(acc[i][2], acc[i][3]);
        }
    }
}

// ---------------- K3: per-bucket LDS CSR build + aggregate ----------------
// 256 threads = 4 waves; block = (bucket, 32-node eighth); scans the 256-node bucket,
// keeps its 32 nodes; each wave aggregates 8 nodes. aggPX stored fp16.
__global__ __launch_bounds__(256) void s2_kernel(
        const float* __restrict__ ps, const float* __restrict__ u, const float* __restrict__ pa,
        const __half2* __restrict__ PX2,
        const unsigned* __restrict__ bktCnt,
        const unsigned long long* __restrict__ bktS, const unsigned long long* __restrict__ bktA,
        __half2* __restrict__ aggPXh, float* __restrict__ Gtail) {
    int b = blockIdx.x >> 3, sub = blockIdx.x & 7;
    int n0 = b * 256 + sub * 32;
    if (n0 >= N_S) return;
    int tid = threadIdx.x;

    __shared__ unsigned listS[32 * CAPN];   // 6 KB
    __shared__ unsigned listA[32 * CAPN];   // 6 KB
    __shared__ unsigned cntL[2][32];
    __shared__ unsigned disL[2][32];

    if (tid < 64) {
        ((unsigned*)cntL)[tid] = 0u;
        ((unsigned*)disL)[tid] = 0u;
    }
    __syncthreads();

    for (int g = 0; g < 2; ++g) {
        const unsigned long long* bp = (g ? bktA : bktS) + (size_t)b * CAPB;
        unsigned cnt = bktCnt[g * NBKT + b];
        if (cnt > CAPB) cnt = CAPB;
        for (unsigned e = tid; e < cnt; e += 256) {
            unsigned long long rr = bp[e];
            int dl = (int)(rr & 255);
            if ((dl >> 5) == sub) {
                int l = dl & 31;
                unsigned disq = (unsigned)((rr >> 24) & 0xFFFF);
                unsigned w = (disq << 16) | (unsigned)((rr >> 8) & 0xFFFF);
                unsigned rk = atomicAdd(&cntL[g][l], 1u);
                atomicAdd(&disL[g][l], disq);
                if (rk < CAPN) {
                    if (g) listA[l * CAPN + rk] = w;
                    else   listS[l * CAPN + rk] = w;
                }
            }
        }
    }
    __syncthreads();

    int wv = tid >> 6, lane = tid & 63;
    for (int i = 0; i < 8; ++i) {
        int l = wv * 8 + i;
        int n = n0 + l;
        if (n >= N_S) break;
        int cS = (int)cntL[0][l];
        int cA = (int)cntL[1][l];
        float sumDisS = (float)disL[0][l] * (1.0f / DISQ);
        float sumDisA = (float)disL[1][l] * (1.0f / DISQ);
        int cSc = cS < CAPN ? cS : CAPN;
        int cAc = cA < CAPN ? cA : CAPN;

        unsigned mywS = (lane < cSc) ? listS[l * CAPN + lane] : 0u;
        unsigned mywA = (lane < cAc) ? listA[l * CAPN + lane] : 0u;

        // ---- s2s: sum projected fp16 rows, 8-deep independent load batches ----
        int myidxS = (int)(mywS & 0xFFFFu);
        float ax = 0.f, ay = 0.f;
        int rounds = (cSc + 7) & ~7;
        for (int j = 0; j < rounds; j += 8) {
            float2 f[8];
            float w[8];
#pragma unroll
            for (int t = 0; t < 8; ++t) {
                int jj = j + t;
                int s = __shfl(myidxS, jj);
                f[t] = __half22float2(PX2[(size_t)s * 64 + lane]);
                w[t] = (jj < cSc) ? 1.f : 0.f;
            }
#pragma unroll
            for (int t = 0; t < 8; ++t) {
                ax += w[t] * f[t].x;
                ay += w[t] * f[t].y;
            }
        }
        float invd = cS > 0 ? 1.f / (float)cS : 0.f;
        aggPXh[(size_t)n * 64 + lane] = __floats2half2_rn(ax * invd, ay * invd);

        // ---- a2s: raw [u16 | pa2] sums; 4 lane-groups, 8 edges in flight ----
        int g2 = lane >> 4, ll = lane & 15;
        int myidxA = (int)(mywA & 0xFFFFu);
        float uacc = 0.f, paacc = 0.f;
        int iters = (cAc + 7) >> 3;
        for (int it = 0; it < iters; ++it) {
            int jj0 = it * 8 + g2;
            int jj1 = jj0 + 4;
            int s0 = __shfl(myidxA, jj0 < 64 ? jj0 : 0);
            int s1 = __shfl(myidxA, jj1 < 64 ? jj1 : 0);
            float w0 = (jj0 < cAc) ? 1.f : 0.f;
            float w1 = (jj1 < cAc) ? 1.f : 0.f;
            float u0 = u[(size_t)s0 * UD + ll];
            float u1 = u[(size_t)s1 * UD + ll];
            float p0 = 0.f, p1 = 0.f;
            if (ll < 2) {
                p0 = pa[s0 * 2 + ll];
                p1 = pa[s1 * 2 + ll];
            }
            uacc += w0 * u0 + w1 * u1;
            if (ll < 2) paacc += w0 * p0 + w1 * p1;
        }
        uacc += __shfl_xor(uacc, 16);
        uacc += __shfl_xor(uacc, 32);
        paacc += __shfl_xor(paacc, 16);
        paacc += __shfl_xor(paacc, 32);
        float us  = __shfl(uacc, (lane >= 2 && lane < 18) ? lane - 2 : 0);
        float pas = __shfl(paacc, (lane >= 18 && lane < 20) ? lane - 18 : 0);

        // ---- Gtail (32 cols) ----
        float psv0 = ps[n * 2], psv1 = ps[n * 2 + 1];
        float e = cS > 0 ? 1.f : 0.f;
        float fcA = (float)cA;
        float v = 0.f;
        if (lane == 0)       v = psv0;
        else if (lane == 1)  v = psv1;
        else if (lane < 18)  v = us;
        else if (lane < 20)  v = pas;
        else if (lane == 20) v = sumDisA;
        else if (lane == 21) v = fcA * psv0;
        else if (lane == 22) v = fcA * psv1;
        else if (lane == 23) v = fcA;
        else if (lane == 24) v = e * psv0;
        else if (lane == 25) v = e * psv1;
        else if (lane == 26) v = e;
        else if (lane == 27) v = invd * sumDisS;
        else if (lane == 28) v = 1.f;
        if (lane < 32) Gtail[(size_t)n * 32 + lane] = v;
    }
}

// ---------------- K4: final GEMM via fp16 MFMA: out = [h|x|Gtail] @ WG + aggPX ----------------
__global__ __launch_bounds__(256) void gemmF_kernel(const float* __restrict__ h,
                                                    const float* __restrict__ x,
                                                    const float* __restrict__ Gtail,
                                                    const _Float16* __restrict__ WGh,
                                                    const __half* __restrict__ aggPXh,
                                                    float* __restrict__ C) {
    int wid = threadIdx.x >> 6, lane = threadIdx.x & 63;
    int mt = blockIdx.x * 4 + wid;           // 16-row tile id
    int row0 = mt * 16;
    int arow = row0 + (lane & 15);
    if (arow >= N_S) arow = N_S - 1;         // clamp; stores guarded below
    int kh = (lane >> 4) * 8;                // k offset within each 32-block

    const float* hp = h + (size_t)arow * HID;
    const float* xp = x + (size_t)arow * XD;
    const float* gp = Gtail + (size_t)arow * 32;

    f16x8 afrag[6];
#pragma unroll
    for (int kb = 0; kb < 6; ++kb) {
        int k = kb * 32 + kh;
        const float* src;
        if (k < 128)      src = hp + k;
        else if (k < 160) src = xp + (k - 128);
        else              src = gp + (k - 160);
        float4 lo = *(const float4*)(src);
        float4 hi = *(const float4*)(src + 4);
        f16x8 a;
        a[0] = (_Float16)lo.x; a[1] = (_Float16)lo.y;
        a[2] = (_Float16)lo.z; a[3] = (_Float16)lo.w;
        a[4] = (_Float16)hi.x; a[5] = (_Float16)hi.y;
        a[6] = (_Float16)hi.z; a[7] = (_Float16)hi.w;
        afrag[kb] = a;
    }

    const f16x8* Bf = (const f16x8*)WGh;     // [(kb*8+nt)*64 + lane]
#pragma unroll
    for (int nt = 0; nt < 8; ++nt) {
        f32x4 acc = {0.f, 0.f, 0.f, 0.f};
#pragma unroll
        for (int kb = 0; kb < 6; ++kb) {
            f16x8 bfr = Bf[(size_t)(kb * 8 + nt) * 64 + lane];
            acc = __builtin_amdgcn_mfma_f32_16x16x32_f16(afrag[kb], bfr, acc, 0, 0, 0);
        }
        int col = nt * 16 + (lane & 15);
        int rbase = row0 + (lane >> 4) * 4;
#pragma unroll
        for (int i = 0; i < 4; ++i) {
            int gr = rbase + i;
            if (gr < N_S) {
                C[(size_t)gr * HID + col] =
                    acc[i] + __half2float(aggPXh[(size_t)gr * HID + col]);
            }
        }
    }
}

extern "C" void kernel_launch(void* const* d_in, const int* in_sizes, int n_in,
                              void* d_out, int out_size, void* d_ws, size_t ws_size,
                              hipStream_t stream) {
    const float* h     = (const float*)d_in[0];
    const float* x     = (const float*)d_in[1];
    const float* u     = (const float*)d_in[2];
    const float* ps    = (const float*)d_in[3];
    const float* pa    = (const float*)d_in[4];
    const float* dis_a = (const float*)d_in[5];
    const float* dis_s = (const float*)d_in[6];
    const int* a2s_src = (const int*)d_in[7];
    const int* a2s_dst = (const int*)d_in[8];
    const int* s2s_src = (const int*)d_in[9];
    const int* s2s_dst = (const int*)d_in[10];
    const float* Wu2h  = (const float*)d_in[11];
    const float* bu2h  = (const float*)d_in[12];
    const float* Wx2h  = (const float*)d_in[13];
    const float* bx2h  = (const float*)d_in[14];
    const float* Wupd  = (const float*)d_in[15];
    const float* bupd  = (const float*)d_in[16];
    float* out = (float*)d_out;

    // Workspace layout (~48.2 MB total):
    char* ws = (char*)d_ws;
    unsigned* bktCnt = (unsigned*)(ws + 0);                       // 392 u32 (pad 4096)
    unsigned long long* bktS = (unsigned long long*)(ws + 4096);  // 196*5120*8 = 8,028,160
    unsigned long long* bktA = (unsigned long long*)(ws + 8032256);
    __half* PX      = (__half*)(ws + 16060416);                   // 12.8 MB
    __half2* aggPXh = (__half2*)(ws + 28860416);                  // 12.8 MB (fp16)
    float* Gtail  = (float*)(ws + 41660416);                      // 6.4 MB
    float* WXsrc  = (float*)(ws + 48060416);                      // 90,112 B
    _Float16* WGh = (_Float16*)(ws + 48150528);                   // 49,152 B

    // K1: zero bucket counters + build WXsrc/WGh
    prep_kernel<<<196, 256, 0, stream>>>(Wu2h, bu2h, Wx2h, bx2h, Wupd, bupd,
                                         WXsrc, WGh, bktCnt);

    // K2: projX (blocks 0..781) overlapped with edge binning (blocks 782..1563)
    phase1_kernel<<<PROJ_NB + 2 * BIN_NB, 256, 0, stream>>>(
        x, h, ps, WXsrc, PX,
        s2s_src, s2s_dst, dis_s, a2s_src, a2s_dst, dis_a,
        bktCnt, bktS, bktA);

    // K3: per-bucket CSR build in LDS + aggregate (256 thr, 32 nodes, grid NBKT*8)
    s2_kernel<<<NBKT * 8, 256, 0, stream>>>(
        ps, u, pa, (const __half2*)PX,
        bktCnt, bktS, bktA, aggPXh, Gtail);

    // K4: final GEMM (MFMA fp16)
    gemmF_kernel<<<PROJ_NB, 256, 0, stream>>>(h, x, Gtail, WGh, (const __half*)aggPXh, out);
}

// Round 9
// 245.744 us; speedup vs baseline: 1.3496x; 1.0100x over previous
//
#include <hip/hip_runtime.h>
#include <hip/hip_fp16.h>

#define N_S 50000
#define N_A 50000
#define E_A 800000
#define E_S 800000
#define HID 128
#define XD 32
#define UD 16

#define KF_PX 176    // projX virtual K: [x32 | h128 | ps2 | pad14]
#define KF_G 192     // final virtual K: [h128 | x32 | tail32]
#define DISQ 65535.0f

#define NBKT 196     // dst buckets of 256 nodes (dst>>8)  -- PROVEN round-6 binning
#define CAPB 5120    // records per bucket (mean 4082, +16 sigma)
#define CAPN 48      // per-node list cap (deg ~Poisson(16), max ~38)

#define BM 64
#define BK 16
#define EPT 8        // edges per bin thread
#define PROJ_NB ((N_S + BM - 1) / BM)                    // 782
#define BIN_NB ((E_S + 256 * EPT - 1) / (256 * EPT))     // 391 per graph

typedef _Float16 f16x8 __attribute__((ext_vector_type(8)));
typedef float f32x4 __attribute__((ext_vector_type(4)));

// ---------------- K1: zero bucket counters + build fused weights ----------------
// WGh in MFMA B-frag order: WGh[((kb*8+nt)*64 + lane)*8 + j]
//   = WG_true[32*kb + (lane>>4)*8 + j][16*nt + (lane&15)]  (fp16)
__global__ void prep_kernel(const float* __restrict__ Wu2h, const float* __restrict__ bu2h,
                            const float* __restrict__ Wx2h, const float* __restrict__ bx2h,
                            const float* __restrict__ Wupd, const float* __restrict__ bupd,
                            float* __restrict__ WXsrc, _Float16* __restrict__ WGh,
                            unsigned* __restrict__ bktCnt) {
    int idx = blockIdx.x * blockDim.x + threadIdx.x;
    if (idx < 2 * NBKT) bktCnt[idx] = 0u;
    if (idx >= (KF_PX + KF_G) * HID) return;
    int r = idx >> 7, j = idx & 127;
    if (r < KF_PX) {
        float v = 0.f;
        if (r < 162) {
            const float* a = Wx2h + (size_t)r * HID;
            float acc = 0.f;
            for (int k = 0; k < HID; ++k) acc += a[k] * Wupd[(258 + k) * HID + j];
            v = acc;
        }
        WXsrc[(size_t)r * HID + j] = v;
        return;
    }
    r -= KF_PX;
    float v = 0.f;
    if (r < 128) {
        v = Wupd[(2 + r) * HID + j];
    } else if (r < 160) {
        v = Wupd[(386 + r - 128) * HID + j];
    } else if (r < 162) {
        v = Wupd[(r - 160) * HID + j];
    } else if (r < 184) {
        const float* a;
        if (r < 180)      a = Wu2h + (size_t)(r - 162) * HID;
        else if (r == 180) a = Wu2h + (size_t)20 * HID;
        else if (r < 183)  a = Wu2h + (size_t)(18 + r - 181) * HID;
        else               a = bu2h;
        float acc = 0.f;
        for (int k = 0; k < HID; ++k) acc += a[k] * Wupd[(130 + k) * HID + j];
        v = acc;
    } else if (r < 188) {
        const float* a;
        if (r < 186)      a = Wx2h + (size_t)(162 + r - 184) * HID;
        else if (r == 186) a = bx2h;
        else               a = Wx2h + (size_t)164 * HID;
        float acc = 0.f;
        for (int k = 0; k < HID; ++k) acc += a[k] * Wupd[(258 + k) * HID + j];
        v = acc;
    } else if (r == 188) {
        v = bupd[j];
    }
    int kb = r >> 5, rr = r & 31;
    int lanehi = rr >> 3, j8 = rr & 7;
    int nt = j >> 4, lanelo = j & 15;
    size_t off = (((size_t)(kb * 8 + nt) * 64) + lanehi * 16 + lanelo) * 8 + j8;
    WGh[off] = (_Float16)v;
}

// ---------------- K2: projX GEMM (blocks 0..781) + edge binning (blocks 782..1563) -------
// bin: record = (bucket<<48)|(disq<<24)|(src<<8)|dstLocal8; LDS-hist + LDS-ordered staging,
// one global atomic per (block,bucket), ~coalesced 8B-record segment flush. [round-6 proven]
__global__ __launch_bounds__(256) void phase1_kernel(
        const float* __restrict__ x, const float* __restrict__ h, const float* __restrict__ ps,
        const float* __restrict__ WXsrc, __half* __restrict__ PX,
        const int* __restrict__ srcS, const int* __restrict__ dstS, const float* __restrict__ disS,
        const int* __restrict__ srcA, const int* __restrict__ dstA, const float* __restrict__ disA,
        unsigned* __restrict__ bktCnt,
        unsigned long long* __restrict__ bktS, unsigned long long* __restrict__ bktA) {
    __shared__ unsigned long long sbuf[2432];   // 19456 B, unioned between paths
    int tid = threadIdx.x;

    if (blockIdx.x >= PROJ_NB) {
        int bid2 = blockIdx.x - PROJ_NB;
        const int* src; const int* dst; const float* dis;
        unsigned long long* bkt; unsigned* bcnt; int nE, base;
        if (bid2 < BIN_NB) {
            src = srcS; dst = dstS; dis = disS; bkt = bktS; bcnt = bktCnt;
            nE = E_S; base = bid2 * (256 * EPT);
        } else {
            src = srcA; dst = dstA; dis = disA; bkt = bktA; bcnt = bktCnt + NBKT;
            nE = E_A; base = (bid2 - BIN_NB) * (256 * EPT);
        }
        unsigned long long* recs = sbuf;                 // 2048 records
        unsigned* hist  = (unsigned*)(sbuf + 2048);      // 256
        unsigned* scan  = hist + 256;                    // 256
        unsigned* gbase = hist + 512;                    // 256

        hist[tid] = 0u;
        __syncthreads();

        unsigned long long rec[EPT]; int bk[EPT]; unsigned rank[EPT];
#pragma unroll
        for (int r = 0; r < EPT; ++r) {
            int t = base + r * 256 + tid;
            bool ok = t < nE;
            int tt = ok ? t : 0;
            int s = __builtin_nontemporal_load(src + tt);
            int d = __builtin_nontemporal_load(dst + tt);
            float f = __builtin_nontemporal_load(dis + tt);
            unsigned disq = (unsigned)(f * DISQ + 0.5f);
            bk[r] = ok ? (d >> 8) : -1;
            rec[r] = ((unsigned long long)(d >> 8) << 48) |
                     ((unsigned long long)disq << 24) |
                     ((unsigned long long)(unsigned)s << 8) |
                     (unsigned long long)(d & 255);
        }
#pragma unroll
        for (int r = 0; r < EPT; ++r)
            if (bk[r] >= 0) rank[r] = atomicAdd(&hist[bk[r]], 1u);
        __syncthreads();

        // inclusive scan of hist -> scan
        scan[tid] = hist[tid];
        __syncthreads();
        for (int off = 1; off < 256; off <<= 1) {
            unsigned v = scan[tid];
            unsigned add = (tid >= off) ? scan[tid - off] : 0u;
            __syncthreads();
            scan[tid] = v + add;
            __syncthreads();
        }

        // stage records LDS-ordered by bucket
#pragma unroll
        for (int r = 0; r < EPT; ++r) {
            if (bk[r] >= 0) {
                unsigned pos = scan[bk[r]] - hist[bk[r]] + rank[r];
                recs[pos] = rec[r];
            }
        }
        // reserve global space per bucket
        if (tid < NBKT) {
            unsigned c = hist[tid];
            gbase[tid] = c ? atomicAdd(&bcnt[tid], c) : 0u;
        }
        __syncthreads();

        int total = (int)scan[255];
        for (int p = tid; p < total; p += 256) {
            unsigned long long rr = recs[p];
            int bb = (int)(rr >> 48);
            unsigned gi = gbase[bb] + (unsigned)p - (scan[bb] - hist[bb]);
            if (gi < CAPB) bkt[(size_t)bb * CAPB + gi] = rr;
        }
        return;
    }

    // ---- projX: PX[N_S x 128] (fp16) = [x|h|ps] @ WXsrc ----
    float* As = (float*)sbuf;            // [BK][BM]
    float* Bs = As + BK * BM;            // [BK][HID]
    int m0 = blockIdx.x * BM;
    int tm = tid >> 5, tn = tid & 31;
    float acc[8][4] = {};
    int la_m = tid >> 2;
    int la_k = (tid & 3) * 4;
    for (int kc = 0; kc < KF_PX; kc += BK) {
        int gm = m0 + la_m;
        int k = kc + la_k;
        float4 av = make_float4(0.f, 0.f, 0.f, 0.f);
        if (gm < N_S) {
            if (k < 32)        av = *(const float4*)(x + (size_t)gm * XD + k);
            else if (k < 160)  av = *(const float4*)(h + (size_t)gm * HID + (k - 32));
            else if (k == 160) av = make_float4(ps[gm * 2], ps[gm * 2 + 1], 0.f, 0.f);
        }
        As[(la_k + 0) * BM + la_m] = av.x;
        As[(la_k + 1) * BM + la_m] = av.y;
        As[(la_k + 2) * BM + la_m] = av.z;
        As[(la_k + 3) * BM + la_m] = av.w;
#pragma unroll
        for (int t2 = 0; t2 < 2; ++t2) {
            int i = tid * 2 + t2;
            int bkk = i >> 5, bn = (i & 31) * 4;
            *(float4*)&Bs[bkk * HID + bn] = *(const float4*)(WXsrc + (size_t)(kc + bkk) * HID + bn);
        }
        __syncthreads();
#pragma unroll
        for (int k2 = 0; k2 < BK; ++k2) {
            float4 a0 = *(float4*)&As[k2 * BM + tm * 8];
            float4 a1 = *(float4*)&As[k2 * BM + tm * 8 + 4];
            float4 b0 = *(float4*)&Bs[k2 * HID + tn * 4];
            float am[8] = {a0.x, a0.y, a0.z, a0.w, a1.x, a1.y, a1.z, a1.w};
            float bv[4] = {b0.x, b0.y, b0.z, b0.w};
#pragma unroll
            for (int i = 0; i < 8; ++i)
#pragma unroll
                for (int j = 0; j < 4; ++j)
                    acc[i][j] += am[i] * bv[j];
        }
        __syncthreads();
    }
    for (int i = 0; i < 8; ++i) {
        int gm = m0 + tm * 8 + i;
        if (gm < N_S) {
            __half2* row = (__half2*)(PX + (size_t)gm * HID);
            row[tn * 2]     = __floats2half2_rn(acc[i][0], acc[i][1]);
            row[tn * 2 + 1] = __floats2half2_rn(acc[i][2], acc[i][3]);
        }
    }
}

// ---------------- K3: per-bucket LDS CSR build + aggregate ----------------
// 256 threads = 4 waves; block = (bucket, 32-node eighth); scans the 256-node bucket,
// keeps its 32 nodes; each wave aggregates 8 nodes. aggPX stored fp16.
// XCD-coherence: b = bid % NBKT, sub = bid / NBKT -> same-bucket subs land on
// dispatch indices differing by 196 (== 4 mod 8) -> only 2 XCDs per bucket under
// round-robin dispatch, so the bucket scan is fetched into ~2 L2s instead of 8.
__global__ __launch_bounds__(256) void s2_kernel(
        const float* __restrict__ ps, const float* __restrict__ u, const float* __restrict__ pa,
        const __half2* __restrict__ PX2,
        const unsigned* __restrict__ bktCnt,
        const unsigned long long* __restrict__ bktS, const unsigned long long* __restrict__ bktA,
        __half2* __restrict__ aggPXh, float* __restrict__ Gtail) {
    int b = blockIdx.x % NBKT, sub = blockIdx.x / NBKT;
    int n0 = b * 256 + sub * 32;
    if (n0 >= N_S) return;
    int tid = threadIdx.x;

    __shared__ unsigned listS[32 * CAPN];   // 6 KB
    __shared__ unsigned listA[32 * CAPN];   // 6 KB
    __shared__ unsigned cntL[2][32];
    __shared__ unsigned disL[2][32];

    if (tid < 64) {
        ((unsigned*)cntL)[tid] = 0u;
        ((unsigned*)disL)[tid] = 0u;
    }
    __syncthreads();

    for (int g = 0; g < 2; ++g) {
        const unsigned long long* bp = (g ? bktA : bktS) + (size_t)b * CAPB;
        unsigned cnt = bktCnt[g * NBKT + b];
        if (cnt > CAPB) cnt = CAPB;
        for (unsigned e = tid; e < cnt; e += 256) {
            unsigned long long rr = bp[e];
            int dl = (int)(rr & 255);
            if ((dl >> 5) == sub) {
                int l = dl & 31;
                unsigned disq = (unsigned)((rr >> 24) & 0xFFFF);
                unsigned w = (disq << 16) | (unsigned)((rr >> 8) & 0xFFFF);
                unsigned rk = atomicAdd(&cntL[g][l], 1u);
                atomicAdd(&disL[g][l], disq);
                if (rk < CAPN) {
                    if (g) listA[l * CAPN + rk] = w;
                    else   listS[l * CAPN + rk] = w;
                }
            }
        }
    }
    __syncthreads();

    int wv = tid >> 6, lane = tid & 63;
    for (int i = 0; i < 8; ++i) {
        int l = wv * 8 + i;
        int n = n0 + l;
        if (n >= N_S) break;
        int cS = (int)cntL[0][l];
        int cA = (int)cntL[1][l];
        float sumDisS = (float)disL[0][l] * (1.0f / DISQ);
        float sumDisA = (float)disL[1][l] * (1.0f / DISQ);
        int cSc = cS < CAPN ? cS : CAPN;
        int cAc = cA < CAPN ? cA : CAPN;

        unsigned mywS = (lane < cSc) ? listS[l * CAPN + lane] : 0u;
        unsigned mywA = (lane < cAc) ? listA[l * CAPN + lane] : 0u;

        // ---- s2s: sum projected fp16 rows, 8-deep independent load batches ----
        int myidxS = (int)(mywS & 0xFFFFu);
        float ax = 0.f, ay = 0.f;
        int rounds = (cSc + 7) & ~7;
        for (int j = 0; j < rounds; j += 8) {
            float2 f[8];
            float w[8];
#pragma unroll
            for (int t = 0; t < 8; ++t) {
                int jj = j + t;
                int s = __shfl(myidxS, jj);
                f[t] = __half22float2(PX2[(size_t)s * 64 + lane]);
                w[t] = (jj < cSc) ? 1.f : 0.f;
            }
#pragma unroll
            for (int t = 0; t < 8; ++t) {
                ax += w[t] * f[t].x;
                ay += w[t] * f[t].y;
            }
        }
        float invd = cS > 0 ? 1.f / (float)cS : 0.f;
        aggPXh[(size_t)n * 64 + lane] = __floats2half2_rn(ax * invd, ay * invd);

        // ---- a2s: raw [u16 | pa2] sums; 4 lane-groups, 8 edges in flight ----
        int g2 = lane >> 4, ll = lane & 15;
        int myidxA = (int)(mywA & 0xFFFFu);
        float uacc = 0.f, paacc = 0.f;
        int iters = (cAc + 7) >> 3;
        for (int it = 0; it < iters; ++it) {
            int jj0 = it * 8 + g2;
            int jj1 = jj0 + 4;
            int s0 = __shfl(myidxA, jj0 < 64 ? jj0 : 0);
            int s1 = __shfl(myidxA, jj1 < 64 ? jj1 : 0);
            float w0 = (jj0 < cAc) ? 1.f : 0.f;
            float w1 = (jj1 < cAc) ? 1.f : 0.f;
            float u0 = u[(size_t)s0 * UD + ll];
            float u1 = u[(size_t)s1 * UD + ll];
            float p0 = 0.f, p1 = 0.f;
            if (ll < 2) {
                p0 = pa[s0 * 2 + ll];
                p1 = pa[s1 * 2 + ll];
            }
            uacc += w0 * u0 + w1 * u1;
            if (ll < 2) paacc += w0 * p0 + w1 * p1;
        }
        uacc += __shfl_xor(uacc, 16);
        uacc += __shfl_xor(uacc, 32);
        paacc += __shfl_xor(paacc, 16);
        paacc += __shfl_xor(paacc, 32);
        float us  = __shfl(uacc, (lane >= 2 && lane < 18) ? lane - 2 : 0);
        float pas = __shfl(paacc, (lane >= 18 && lane < 20) ? lane - 18 : 0);

        // ---- Gtail (32 cols) ----
        float psv0 = ps[n * 2], psv1 = ps[n * 2 + 1];
        float e = cS > 0 ? 1.f : 0.f;
        float fcA = (float)cA;
        float v = 0.f;
        if (lane == 0)       v = psv0;
        else if (lane == 1)  v = psv1;
        else if (lane < 18)  v = us;
        else if (lane < 20)  v = pas;
        else if (lane == 20) v = sumDisA;
        else if (lane == 21) v = fcA * psv0;
        else if (lane == 22) v = fcA * psv1;
        else if (lane == 23) v = fcA;
        else if (lane == 24) v = e * psv0;
        else if (lane == 25) v = e * psv1;
        else if (lane == 26) v = e;
        else if (lane == 27) v = invd * sumDisS;
        else if (lane == 28) v = 1.f;
        if (lane < 32) Gtail[(size_t)n * 32 + lane] = v;
    }
}

// ---------------- K4: final GEMM via fp16 MFMA: out = [h|x|Gtail] @ WG + aggPX ----------------
__global__ __launch_bounds__(256) void gemmF_kernel(const float* __restrict__ h,
                                                    const float* __restrict__ x,
                                                    const float* __restrict__ Gtail,
                                                    const _Float16* __restrict__ WGh,
                                                    const __half* __restrict__ aggPXh,
                                                    float* __restrict__ C) {
    int wid = threadIdx.x >> 6, lane = threadIdx.x & 63;
    int mt = blockIdx.x * 4 + wid;           // 16-row tile id
    int row0 = mt * 16;
    int arow = row0 + (lane & 15);
    if (arow >= N_S) arow = N_S - 1;         // clamp; stores guarded below
    int kh = (lane >> 4) * 8;                // k offset within each 32-block

    const float* hp = h + (size_t)arow * HID;
    const float* xp = x + (size_t)arow * XD;
    const float* gp = Gtail + (size_t)arow * 32;

    f16x8 afrag[6];
#pragma unroll
    for (int kb = 0; kb < 6; ++kb) {
        int k = kb * 32 + kh;
        const float* src;
        if (k < 128)      src = hp + k;
        else if (k < 160) src = xp + (k - 128);
        else              src = gp + (k - 160);
        float4 lo = *(const float4*)(src);
        float4 hi = *(const float4*)(src + 4);
        f16x8 a;
        a[0] = (_Float16)lo.x; a[1] = (_Float16)lo.y;
        a[2] = (_Float16)lo.z; a[3] = (_Float16)lo.w;
        a[4] = (_Float16)hi.x; a[5] = (_Float16)hi.y;
        a[6] = (_Float16)hi.z; a[7] = (_Float16)hi.w;
        afrag[kb] = a;
    }

    const f16x8* Bf = (const f16x8*)WGh;     // [(kb*8+nt)*64 + lane]
#pragma unroll
    for (int nt = 0; nt < 8; ++nt) {
        f32x4 acc = {0.f, 0.f, 0.f, 0.f};
#pragma unroll
        for (int kb = 0; kb < 6; ++kb) {
            f16x8 bfr = Bf[(size_t)(kb * 8 + nt) * 64 + lane];
            acc = __builtin_amdgcn_mfma_f32_16x16x32_f16(afrag[kb], bfr, acc, 0, 0, 0);
        }
        int col = nt * 16 + (lane & 15);
        int rbase = row0 + (lane >> 4) * 4;
#pragma unroll
        for (int i = 0; i < 4; ++i) {
            int gr = rbase + i;
            if (gr < N_S) {
                C[(size_t)gr * HID + col] =
                    acc[i] + __half2float(aggPXh[(size_t)gr * HID + col]);
            }
        }
    }
}

extern "C" void kernel_launch(void* const* d_in, const int* in_sizes, int n_in,
                              void* d_out, int out_size, void* d_ws, size_t ws_size,
                              hipStream_t stream) {
    const float* h     = (const float*)d_in[0];
    const float* x     = (const float*)d_in[1];
    const float* u     = (const float*)d_in[2];
    const float* ps    = (const float*)d_in[3];
    const float* pa    = (const float*)d_in[4];
    const float* dis_a = (const float*)d_in[5];
    const float* dis_s = (const float*)d_in[6];
    const int* a2s_src = (const int*)d_in[7];
    const int* a2s_dst = (const int*)d_in[8];
    const int* s2s_src = (const int*)d_in[9];
    const int* s2s_dst = (const int*)d_in[10];
    const float* Wu2h  = (const float*)d_in[11];
    const float* bu2h  = (const float*)d_in[12];
    const float* Wx2h  = (const float*)d_in[13];
    const float* bx2h  = (const float*)d_in[14];
    const float* Wupd  = (const float*)d_in[15];
    const float* bupd  = (const float*)d_in[16];
    float* out = (float*)d_out;

    // Workspace layout (~48.2 MB total):
    char* ws = (char*)d_ws;
    unsigned* bktCnt = (unsigned*)(ws + 0);                       // 392 u32 (pad 4096)
    unsigned long long* bktS = (unsigned long long*)(ws + 4096);  // 196*5120*8 = 8,028,160
    unsigned long long* bktA = (unsigned long long*)(ws + 8032256);
    __half* PX      = (__half*)(ws + 16060416);                   // 12.8 MB
    __half2* aggPXh = (__half2*)(ws + 28860416);                  // 12.8 MB (fp16)
    float* Gtail  = (float*)(ws + 41660416);                      // 6.4 MB
    float* WXsrc  = (float*)(ws + 48060416);                      // 90,112 B
    _Float16* WGh = (_Float16*)(ws + 48150528);                   // 49,152 B

    // K1: zero bucket counters + build WXsrc/WGh
    prep_kernel<<<196, 256, 0, stream>>>(Wu2h, bu2h, Wx2h, bx2h, Wupd, bupd,
                                         WXsrc, WGh, bktCnt);

    // K2: projX (blocks 0..781) overlapped with edge binning (blocks 782..1563)
    phase1_kernel<<<PROJ_NB + 2 * BIN_NB, 256, 0, stream>>>(
        x, h, ps, WXsrc, PX,
        s2s_src, s2s_dst, dis_s, a2s_src, a2s_dst, dis_a,
        bktCnt, bktS, bktA);

    // K3: per-bucket CSR build in LDS + aggregate (256 thr, 32 nodes, grid NBKT*8,
    //     XCD-coherent sub mapping)
    s2_kernel<<<NBKT * 8, 256, 0, stream>>>(
        ps, u, pa, (const __half2*)PX,
        bktCnt, bktS, bktA, aggPXh, Gtail);

    // K4: final GEMM (MFMA fp16)
    gemmF_kernel<<<PROJ_NB, 256, 0, stream>>>(h, x, Gtail, WGh, (const __half*)aggPXh, out);
}